// Round 6
// baseline (1000.570 us; speedup 1.0000x reference)
//
#include <hip/hip_runtime.h>
#include <hip/hip_bf16.h>

#define N_NODES 100000
#define N_EDGES 1600000
#define NPB 32               // nodes per fused block (100000 = 32*3125 exactly)

typedef short s8v __attribute__((ext_vector_type(8)));
typedef float f4v __attribute__((ext_vector_type(4)));
typedef unsigned short us4 __attribute__((ext_vector_type(4)));

__device__ inline unsigned short f2bfn(float f) {
    __hip_bfloat16 h = __float2bfloat16(f);
    unsigned short u;
    __builtin_memcpy(&u, &h, 2);
    return u;
}

__device__ inline float silu_f(float v) {
    return v * __builtin_amdgcn_rcpf(1.0f + __expf(-v));
}

__device__ inline f4v splat4(float v) {
    f4v r;
    r[0] = v; r[1] = v; r[2] = v; r[3] = v;
    return r;
}

// ---------------------------------------------------------------------------
// Prepass: x (f32, [N,64]) -> bf16 copy in workspace.
// ---------------------------------------------------------------------------
__global__ __launch_bounds__(256) void x2bf_kernel(const float* __restrict__ x,
                                                   unsigned short* __restrict__ xb)
{
    const int total = N_NODES * 64 / 4;
    for (int i = blockIdx.x * blockDim.x + threadIdx.x; i < total;
         i += gridDim.x * blockDim.x) {
        f4v v = *(const f4v*)(x + (size_t)i * 4);
        us4 o;
        #pragma unroll
        for (int q = 0; q < 4; ++q) o[q] = f2bfn(v[q]);
        *(us4*)(xb + (size_t)i * 4) = o;
    }
}

// ---------------------------------------------------------------------------
// Weight prep: fragment-ordered bf16 copies (done once, tiny).
// ---------------------------------------------------------------------------
__global__ __launch_bounds__(256) void wprep_kernel(
    const float* __restrict__ We1, const float* __restrict__ We2,
    const float* __restrict__ Wn1, const float* __restrict__ Wn2,
    unsigned short* __restrict__ w1p, unsigned short* __restrict__ w2p,
    unsigned short* __restrict__ wn1p, unsigned short* __restrict__ wn2p)
{
    const int stride = gridDim.x * blockDim.x;
    const int tid0 = blockIdx.x * blockDim.x + threadIdx.x;
    for (int i = tid0; i < 64 * 160; i += stride) {
        int row = i / 160, k = i - row * 160;
        int t = row >> 4, lr = row & 15, s = k >> 5, kg = (k >> 3) & 3, j = k & 7;
        w1p[(((t * 5 + s) * 64) + (kg * 16 + lr)) * 8 + j] = f2bfn(We1[i]);
    }
    for (int i = tid0; i < 64 * 64; i += stride) {
        int row = i >> 6, k = i & 63;
        int t = row >> 4, lr = row & 15, s = k >> 5, kg = (k >> 3) & 3, j = k & 7;
        w2p[(((t * 2 + s) * 64) + (kg * 16 + lr)) * 8 + j] = f2bfn(We2[i]);
    }
    for (int i = tid0; i < 64 * 128; i += stride) {
        int row = i >> 7, k = i & 127;
        int t = row >> 4, lr = row & 15, s = k >> 5, kg = (k >> 3) & 3, j = k & 7;
        wn1p[(((t * 4 + s) * 64) + (kg * 16 + lr)) * 8 + j] = f2bfn(Wn1[i]);
    }
    for (int i = tid0; i < 64 * 64; i += stride) {
        int row = i >> 6, k = i & 63;
        int t = row >> 4, lr = row & 15, s = k >> 5, kg = (k >> 3) & 3, j = k & 7;
        wn2p[(((t * 2 + s) * 64) + (kg * 16 + lr)) * 8 + j] = f2bfn(Wn2[i]);
    }
}

// ---------------------------------------------------------------------------
// CSR build: histogram -> 2-level scan -> permutation
// ---------------------------------------------------------------------------
__global__ __launch_bounds__(256) void hist_kernel(const int* __restrict__ eidx,
                                                   int* cnt)
{
    for (int e = blockIdx.x * blockDim.x + threadIdx.x; e < N_EDGES;
         e += gridDim.x * blockDim.x)
        atomicAdd(&cnt[eidx[e]], 1);
}

#define SCAN_NBLK 98   // 98*1024 >= 100000

__global__ __launch_bounds__(1024) void scanA_kernel(const int* __restrict__ cnt,
                                                     int* base, int* bsum)
{
    __shared__ int sh[1024];
    const int t = threadIdx.x;
    const int i = blockIdx.x * 1024 + t;
    int c = (i < N_NODES) ? cnt[i] : 0;
    sh[t] = c;
    __syncthreads();
    for (int off = 1; off < 1024; off <<= 1) {
        int v = (t >= off) ? sh[t - off] : 0;
        __syncthreads();
        sh[t] += v;
        __syncthreads();
    }
    if (i < N_NODES) base[i] = sh[t];          // inclusive for now
    if (t == 1023) bsum[blockIdx.x] = sh[1023];
}

__global__ __launch_bounds__(128) void scanB_kernel(const int* __restrict__ bsum,
                                                    int* boff)
{
    __shared__ int sh[128];
    const int t = threadIdx.x;
    int v = (t < SCAN_NBLK) ? bsum[t] : 0;
    sh[t] = v;
    __syncthreads();
    for (int off = 1; off < 128; off <<= 1) {
        int u = (t >= off) ? sh[t - off] : 0;
        __syncthreads();
        sh[t] += u;
        __syncthreads();
    }
    boff[t] = sh[t] - v;   // exclusive
}

__global__ __launch_bounds__(256) void scanC_kernel(const int* __restrict__ cnt,
                                                    int* base, const int* __restrict__ boff,
                                                    int* cur)
{
    const int i = blockIdx.x * 256 + threadIdx.x;
    if (i < N_NODES) {
        int b = base[i] - cnt[i] + boff[i >> 10];   // exclusive prefix
        base[i] = b;
        cur[i]  = b;
    }
}

// elist entry: .x = e | rloc<<25  (e < 2^21, rloc 5b), .y = col
__global__ __launch_bounds__(256) void perm_kernel(const int* __restrict__ eidx,
                                                   int* cur, int2* __restrict__ elist)
{
    for (int e = blockIdx.x * blockDim.x + threadIdx.x; e < N_EDGES;
         e += gridDim.x * blockDim.x) {
        int r = eidx[e];
        int c = eidx[N_EDGES + e];
        int pos = atomicAdd(&cur[r], 1);
        elist[pos] = make_int2(e | ((r & (NPB - 1)) << 25), c);
    }
}

// ---------------------------------------------------------------------------
// Fused kernel: block = 32 nodes + all their edges.
// LDS: W1L 20480 + W2L 8192 + HL 16384 + AGG 8448 = 53504 B -> 3 blocks/CU.
// ---------------------------------------------------------------------------
__global__ __launch_bounds__(512, 6) void fused_kernel(
    const unsigned short* __restrict__ xb, const float* __restrict__ ef,
    const int* __restrict__ base, const int2* __restrict__ elist,
    const unsigned short* __restrict__ w1p, const unsigned short* __restrict__ w2p,
    const unsigned short* __restrict__ wn1p, const unsigned short* __restrict__ wn2p,
    const float* __restrict__ be1, const float* __restrict__ be2,
    const float* __restrict__ bn1, const float* __restrict__ bn2,
    float* __restrict__ out)
{
    __shared__ unsigned short W1L[20 * 64 * 8];    // 20480 B
    __shared__ unsigned short W2L[8 * 64 * 8];     //  8192 B
    __shared__ unsigned short HL[8][2][64][8];     // 16384 B
    __shared__ float AGG[NPB + 1][64];             //  8448 B (row NPB = trash)

    const int tid = threadIdx.x;

    // --- stage weights: pure vector copy (pre-formatted) + zero AGG ---
    {
        const s8v* s1 = (const s8v*)w1p;  s8v* d1 = (s8v*)W1L;
        for (int i = tid; i < 20 * 64; i += 512) d1[i] = s1[i];
        const s8v* s2 = (const s8v*)w2p;  s8v* d2 = (s8v*)W2L;
        for (int i = tid; i < 8 * 64; i += 512) d2[i] = s2[i];
    }
    for (int i = tid; i < (NPB + 1) * 64; i += 512) ((float*)AGG)[i] = 0.0f;
    __syncthreads();

    const int lane = tid & 63;
    const int wv   = tid >> 6;      // 0..7
    const int lrow = lane & 15;
    const int lkg  = lane >> 4;

    const int n0    = blockIdx.x * NPB;
    const int base0 = base[n0];
    // STRICT <: when n0+NPB == N_NODES (exact last block), base[N_NODES] is
    // out of bounds (aliases cur[0]) -> must use N_EDGES.  [round-5 bug]
    const int end   = (n0 + NPB < N_NODES) ? base[n0 + NPB] : N_EDGES;

    float b1f[4], b2f[4];
    #pragma unroll
    for (int t = 0; t < 4; ++t) {
        b1f[t] = be1[t * 16 + lrow];
        b2f[t] = be2[t * 16 + lrow];
    }

    // ---------------- edge phase (no barriers, waves independent) ----------
    int t0 = base0 + wv * 16;
    if (t0 < end) {
        int idx0 = t0 + lrow;
        int2 ent = elist[(idx0 < end) ? idx0 : base0];

        for (; t0 < end; t0 += 8 * 16) {
            const int  idx   = t0 + lrow;
            const bool valid = idx < end;
            const int ar    = valid ? (ent.x >> 25) : NPB;    // NPB = trash row
            const int e     = ent.x & 0x1FFFFFF;
            const int c     = ent.y;
            const int rowid = n0 + (ent.x >> 25);             // L1-hot (32 rows)

            // gather current A-fragments
            s8v afr[5];
            afr[0] = *(const s8v*)(xb + (size_t)rowid * 64 + lkg * 8);
            afr[1] = *(const s8v*)(xb + (size_t)rowid * 64 + 32 + lkg * 8);
            afr[2] = *(const s8v*)(xb + (size_t)c * 64 + lkg * 8);
            afr[3] = *(const s8v*)(xb + (size_t)c * 64 + 32 + lkg * 8);
            const float* ep = ef + (size_t)e * 32 + lkg * 8;
            f4v elo = *(const f4v*)ep;
            f4v ehi = *(const f4v*)(ep + 4);

            // prefetch next iteration's elist entry (hides one serial hop)
            const int tn = t0 + 8 * 16;
            if (tn < end) {
                int idxn = tn + lrow;
                ent = elist[(idxn < end) ? idxn : base0];
            }

            {
                s8v a4;
                #pragma unroll
                for (int q = 0; q < 4; ++q) {
                    a4[q]     = (short)f2bfn(elo[q]);
                    a4[q + 4] = (short)f2bfn(ehi[q]);
                }
                afr[4] = a4;
            }

            // GEMM1 [16,160] x [160,64]; bias folded into C-init
            f4v acc[4];
            #pragma unroll
            for (int t = 0; t < 4; ++t) acc[t] = splat4(b1f[t]);
            #pragma unroll
            for (int s = 0; s < 5; ++s) {
                #pragma unroll
                for (int t = 0; t < 4; ++t) {
                    s8v b = *(const s8v*)&W1L[((t * 5 + s) * 64 + lane) * 8];
                    acc[t] = __builtin_amdgcn_mfma_f32_16x16x32_bf16(afr[s], b, acc[t], 0, 0, 0);
                }
            }

            // silu -> HL (wave-private, fragment-major)
            #pragma unroll
            for (int t = 0; t < 4; ++t) {
                const int col = t * 16 + lrow;
                const int s = col >> 5, lsub = (col & 31) >> 3, j = col & 7;
                #pragma unroll
                for (int rr = 0; rr < 4; ++rr)
                    HL[wv][s][lsub * 16 + (lkg * 4 + rr)][j] = f2bfn(silu_f(acc[t][rr]));
            }

            // GEMM2 [16,64] x [64,64]; bias folded into C-init
            s8v h0 = *(const s8v*)&HL[wv][0][lane][0];
            s8v h1 = *(const s8v*)&HL[wv][1][lane][0];
            f4v c2[4];
            #pragma unroll
            for (int t = 0; t < 4; ++t) c2[t] = splat4(b2f[t]);
            #pragma unroll
            for (int t = 0; t < 4; ++t) {
                s8v b0 = *(const s8v*)&W2L[((t * 2 + 0) * 64 + lane) * 8];
                s8v b1 = *(const s8v*)&W2L[((t * 2 + 1) * 64 + lane) * 8];
                c2[t] = __builtin_amdgcn_mfma_f32_16x16x32_bf16(h0, b0, c2[t], 0, 0, 0);
                c2[t] = __builtin_amdgcn_mfma_f32_16x16x32_bf16(h1, b1, c2[t], 0, 0, 0);
            }

            // silu -> LDS segment-sum
            #pragma unroll
            for (int rr = 0; rr < 4; ++rr) {
                const int arb = __shfl(ar, lkg * 4 + rr);
                #pragma unroll
                for (int t = 0; t < 4; ++t)
                    atomicAdd(&AGG[arb][t * 16 + lrow], silu_f(c2[t][rr]));
            }
        }
    }
    __syncthreads();

    // ---------------- node phase (waves 0..1, 16 rows each) ----------------
    if (wv < 2) {
        const int m0 = wv * 16;
        float n1f[4], n2f[4];
        #pragma unroll
        for (int t = 0; t < 4; ++t) {
            n1f[t] = bn1[t * 16 + lrow];
            n2f[t] = bn2[t * 16 + lrow];
        }

        const int n = n0 + m0 + lrow;   // 100000 % 32 == 0: no tail

        s8v a[4];
        a[0] = *(const s8v*)(xb + (size_t)n * 64 + lkg * 8);
        a[1] = *(const s8v*)(xb + (size_t)n * 64 + 32 + lkg * 8);
        #pragma unroll
        for (int s = 0; s < 2; ++s) {
            f4v g0 = *(const f4v*)&AGG[m0 + lrow][s * 32 + lkg * 8];
            f4v g1 = *(const f4v*)&AGG[m0 + lrow][s * 32 + lkg * 8 + 4];
            s8v av;
            #pragma unroll
            for (int q = 0; q < 4; ++q) {
                av[q]     = (short)f2bfn(g0[q]);
                av[q + 4] = (short)f2bfn(g1[q]);
            }
            a[2 + s] = av;
        }

        // GEMM1 [16,128] x [128,64]; B-frags straight from global (L2-hot)
        f4v acc[4];
        #pragma unroll
        for (int t = 0; t < 4; ++t) acc[t] = splat4(n1f[t]);
        #pragma unroll
        for (int s = 0; s < 4; ++s) {
            #pragma unroll
            for (int t = 0; t < 4; ++t) {
                s8v b = ((const s8v*)wn1p)[(t * 4 + s) * 64 + lane];
                acc[t] = __builtin_amdgcn_mfma_f32_16x16x32_bf16(a[s], b, acc[t], 0, 0, 0);
            }
        }

        #pragma unroll
        for (int t = 0; t < 4; ++t) {
            const int col = t * 16 + lrow;
            const int s = col >> 5, lsub = (col & 31) >> 3, j = col & 7;
            #pragma unroll
            for (int rr = 0; rr < 4; ++rr)
                HL[wv][s][lsub * 16 + (lkg * 4 + rr)][j] = f2bfn(silu_f(acc[t][rr]));
        }

        s8v h0 = *(const s8v*)&HL[wv][0][lane][0];
        s8v h1 = *(const s8v*)&HL[wv][1][lane][0];
        f4v c2[4];
        #pragma unroll
        for (int t = 0; t < 4; ++t) c2[t] = splat4(n2f[t]);
        #pragma unroll
        for (int t = 0; t < 4; ++t) {
            s8v b0 = ((const s8v*)wn2p)[(t * 2 + 0) * 64 + lane];
            s8v b1 = ((const s8v*)wn2p)[(t * 2 + 1) * 64 + lane];
            c2[t] = __builtin_amdgcn_mfma_f32_16x16x32_bf16(h0, b0, c2[t], 0, 0, 0);
            c2[t] = __builtin_amdgcn_mfma_f32_16x16x32_bf16(h1, b1, c2[t], 0, 0, 0);
        }

        #pragma unroll
        for (int rr = 0; rr < 4; ++rr) {
            float* dst = out + (size_t)(n0 + m0 + lkg * 4 + rr) * 64;
            #pragma unroll
            for (int t = 0; t < 4; ++t)
                dst[t * 16 + lrow] = c2[t][rr];
        }
    }
}

// ---------------------------------------------------------------------------
// Fallback (round-2 path) if ws is too small.
// ---------------------------------------------------------------------------
__global__ __launch_bounds__(256, 4) void edge_kernel_fb(
    const unsigned short* __restrict__ xb, const int* __restrict__ eidx,
    const float* __restrict__ ef,
    const float* __restrict__ We1, const float* __restrict__ be1,
    const float* __restrict__ We2, const float* __restrict__ be2,
    float* agg)
{
    __shared__ unsigned short W1L[64 * 160];
    __shared__ unsigned short W2L[64 * 64];
    __shared__ unsigned short HL[4][2][64][8];

    const int tid = threadIdx.x;
    for (int i = tid; i < 64 * 160; i += 256) {
        int row = i / 160, k = i - row * 160;
        int t = row >> 4, lr = row & 15, s = k >> 5, kg = (k >> 3) & 3, j = k & 7;
        W1L[(((t * 5 + s) * 64) + (kg * 16 + lr)) * 8 + j] = f2bfn(We1[i]);
    }
    for (int i = tid; i < 64 * 64; i += 256) {
        int row = i >> 6, k = i & 63;
        int t = row >> 4, lr = row & 15, s = k >> 5, kg = (k >> 3) & 3, j = k & 7;
        W2L[(((t * 2 + s) * 64) + (kg * 16 + lr)) * 8 + j] = f2bfn(We2[i]);
    }
    __syncthreads();

    const int lane = tid & 63, wv = tid >> 6, lrow = lane & 15, lkg = lane >> 4;
    float b1f[4], b2f[4];
    #pragma unroll
    for (int t = 0; t < 4; ++t) { b1f[t] = be1[t*16+lrow]; b2f[t] = be2[t*16+lrow]; }

    const int wave_id = blockIdx.x * 4 + wv, n_waves = gridDim.x * 4;
    for (int grp = wave_id; grp < N_EDGES / 16; grp += n_waves) {
        const int e0 = grp * 16;
        const int r = eidx[e0 + lrow];
        const int c = eidx[N_EDGES + e0 + lrow];
        s8v afr[5];
        afr[0] = *(const s8v*)(xb + (size_t)r * 64 + lkg * 8);
        afr[1] = *(const s8v*)(xb + (size_t)r * 64 + 32 + lkg * 8);
        afr[2] = *(const s8v*)(xb + (size_t)c * 64 + lkg * 8);
        afr[3] = *(const s8v*)(xb + (size_t)c * 64 + 32 + lkg * 8);
        {
            const float* ep = ef + (size_t)(e0 + lrow) * 32 + lkg * 8;
            f4v elo = *(const f4v*)ep, ehi = *(const f4v*)(ep + 4);
            s8v a4;
            #pragma unroll
            for (int q = 0; q < 4; ++q) { a4[q] = (short)f2bfn(elo[q]); a4[q+4] = (short)f2bfn(ehi[q]); }
            afr[4] = a4;
        }
        f4v acc[4];
        #pragma unroll
        for (int t = 0; t < 4; ++t) acc[t] = splat4(b1f[t]);
        #pragma unroll
        for (int s = 0; s < 5; ++s)
            #pragma unroll
            for (int t = 0; t < 4; ++t) {
                s8v b = *(const s8v*)&W1L[((t * 5 + s) * 64 + lane) * 8];
                acc[t] = __builtin_amdgcn_mfma_f32_16x16x32_bf16(afr[s], b, acc[t], 0, 0, 0);
            }
        #pragma unroll
        for (int t = 0; t < 4; ++t) {
            const int col = t*16+lrow, s = col >> 5, lsub = (col & 31) >> 3, j = col & 7;
            #pragma unroll
            for (int rr = 0; rr < 4; ++rr)
                HL[wv][s][lsub*16 + (lkg*4+rr)][j] = f2bfn(silu_f(acc[t][rr]));
        }
        s8v h0 = *(const s8v*)&HL[wv][0][lane][0];
        s8v h1 = *(const s8v*)&HL[wv][1][lane][0];
        f4v c2[4];
        #pragma unroll
        for (int t = 0; t < 4; ++t) c2[t] = splat4(b2f[t]);
        #pragma unroll
        for (int t = 0; t < 4; ++t) {
            s8v b0 = *(const s8v*)&W2L[((t*2+0)*64+lane)*8];
            s8v b1 = *(const s8v*)&W2L[((t*2+1)*64+lane)*8];
            c2[t] = __builtin_amdgcn_mfma_f32_16x16x32_bf16(h0, b0, c2[t], 0, 0, 0);
            c2[t] = __builtin_amdgcn_mfma_f32_16x16x32_bf16(h1, b1, c2[t], 0, 0, 0);
        }
        #pragma unroll
        for (int rr = 0; rr < 4; ++rr) {
            const int node = __shfl(r, lkg * 4 + rr);
            float* dst = agg + (size_t)node * 64;
            #pragma unroll
            for (int t = 0; t < 4; ++t)
                atomicAdd(dst + t * 16 + lrow, silu_f(c2[t][rr]));
        }
    }
}

__global__ __launch_bounds__(256) void node_kernel_fb(
    const float* __restrict__ x,
    const float* __restrict__ Wn1, const float* __restrict__ bn1,
    const float* __restrict__ Wn2, const float* __restrict__ bn2,
    float* io)
{
    __shared__ unsigned short A[64][136];
    __shared__ unsigned short W1[64][136];
    __shared__ unsigned short H[64][72];
    __shared__ unsigned short W2[64][72];
    __shared__ float B1[64];
    __shared__ float B2[64];

    const int tid = threadIdx.x;
    for (int i = tid; i < 64 * 128; i += 256) W1[i >> 7][i & 127] = f2bfn(Wn1[i]);
    for (int i = tid; i < 64 * 64; i += 256) W2[i >> 6][i & 63] = f2bfn(Wn2[i]);
    if (tid < 64) { B1[tid] = bn1[tid]; B2[tid] = bn2[tid]; }

    const int n0 = blockIdx.x * 64, g = tid >> 4, l16 = tid & 15;
    #pragma unroll
    for (int i = 0; i < 4; ++i) {
        int e = g + i * 16, n = n0 + e;
        if (n >= N_NODES) n = N_NODES - 1;
        f4v xv = *(const f4v*)(x + (size_t)n * 64 + l16 * 4);
        us4 av;
        #pragma unroll
        for (int q = 0; q < 4; ++q) av[q] = f2bfn(xv[q]);
        *(us4*)&A[e][l16 * 4] = av;
        f4v gv = *(const f4v*)(io + (size_t)n * 64 + l16 * 4);
        us4 ag;
        #pragma unroll
        for (int q = 0; q < 4; ++q) ag[q] = f2bfn(gv[q]);
        *(us4*)&A[e][64 + l16 * 4] = ag;
    }
    __syncthreads();

    const int lane = tid & 63, m0 = (tid >> 6) * 16, lrow = lane & 15, lkg = lane >> 4;
    f4v a0 = 0, a1 = 0, a2 = 0, a3 = 0;
    #pragma unroll
    for (int s = 0; s < 4; ++s) {
        int k0 = s * 32 + lkg * 8;
        s8v av = *(const s8v*)&A[m0 + lrow][k0];
        a0 = __builtin_amdgcn_mfma_f32_16x16x32_bf16(av, *(const s8v*)&W1[ 0+lrow][k0], a0, 0, 0, 0);
        a1 = __builtin_amdgcn_mfma_f32_16x16x32_bf16(av, *(const s8v*)&W1[16+lrow][k0], a1, 0, 0, 0);
        a2 = __builtin_amdgcn_mfma_f32_16x16x32_bf16(av, *(const s8v*)&W1[32+lrow][k0], a2, 0, 0, 0);
        a3 = __builtin_amdgcn_mfma_f32_16x16x32_bf16(av, *(const s8v*)&W1[48+lrow][k0], a3, 0, 0, 0);
    }
    {
        f4v accs[4] = {a0, a1, a2, a3};
        #pragma unroll
        for (int t = 0; t < 4; ++t) {
            int col = t * 16 + lrow;
            float bias = B1[col];
            #pragma unroll
            for (int r = 0; r < 4; ++r)
                H[m0 + lkg * 4 + r][col] = f2bfn(silu_f(accs[t][r] + bias));
        }
    }
    f4v c0 = 0, c1 = 0, c2 = 0, c3 = 0;
    #pragma unroll
    for (int s = 0; s < 2; ++s) {
        int k0 = s * 32 + lkg * 8;
        s8v av = *(const s8v*)&H[m0 + lrow][k0];
        c0 = __builtin_amdgcn_mfma_f32_16x16x32_bf16(av, *(const s8v*)&W2[ 0+lrow][k0], c0, 0, 0, 0);
        c1 = __builtin_amdgcn_mfma_f32_16x16x32_bf16(av, *(const s8v*)&W2[16+lrow][k0], c1, 0, 0, 0);
        c2 = __builtin_amdgcn_mfma_f32_16x16x32_bf16(av, *(const s8v*)&W2[32+lrow][k0], c2, 0, 0, 0);
        c3 = __builtin_amdgcn_mfma_f32_16x16x32_bf16(av, *(const s8v*)&W2[48+lrow][k0], c3, 0, 0, 0);
    }
    {
        f4v cs[4] = {c0, c1, c2, c3};
        #pragma unroll
        for (int r = 0; r < 4; ++r) {
            int n = n0 + m0 + lkg * 4 + r;
            if (n < N_NODES) {
                float* dst = io + (size_t)n * 64;
                #pragma unroll
                for (int t = 0; t < 4; ++t) dst[t * 16 + lrow] = cs[t][r] + B2[t * 16 + lrow];
            }
        }
    }
}

extern "C" void kernel_launch(void* const* d_in, const int* in_sizes, int n_in,
                              void* d_out, int out_size, void* d_ws, size_t ws_size,
                              hipStream_t stream) {
    const float* x    = (const float*)d_in[0];
    const int*   eidx = (const int*)  d_in[1];
    const float* ef   = (const float*)d_in[2];
    const float* We1  = (const float*)d_in[3];
    const float* be1  = (const float*)d_in[4];
    const float* We2  = (const float*)d_in[5];
    const float* be2  = (const float*)d_in[6];
    const float* Wn1  = (const float*)d_in[7];
    const float* bn1  = (const float*)d_in[8];
    const float* Wn2  = (const float*)d_in[9];
    const float* bn2  = (const float*)d_in[10];
    float* out = (float*)d_out;

    char* ws = (char*)d_ws;
    // ws layout (bytes)
    unsigned short* xb   = (unsigned short*)ws;                  // 12,800,000
    int*  cnt   = (int*) (ws + 12800000);                        //    400,000
    int*  basep = (int*) (ws + 13200000);                        //    400,000
    int*  cur   = (int*) (ws + 13600000);                        //    400,000
    int*  bsum  = (int*) (ws + 14000000);                        //        512
    int*  boff  = (int*) (ws + 14000512);                        //        512
    unsigned short* w1p  = (unsigned short*)(ws + 14001024);     //     20,480
    unsigned short* w2p  = (unsigned short*)(ws + 14021504);     //      8,192
    unsigned short* wn1p = (unsigned short*)(ws + 14029696);     //     16,384
    unsigned short* wn2p = (unsigned short*)(ws + 14046080);     //      8,192
    int2* elist = (int2*)(ws + 14054272);                        // 12,800,000
    const size_t WS_NEEDED = 26854272;

    x2bf_kernel<<<1024, 256, 0, stream>>>(x, xb);

    if (ws_size >= WS_NEEDED) {
        wprep_kernel<<<64, 256, 0, stream>>>(We1, We2, Wn1, Wn2, w1p, w2p, wn1p, wn2p);
        hipMemsetAsync(cnt, 0, N_NODES * sizeof(int), stream);
        hist_kernel<<<2048, 256, 0, stream>>>(eidx, cnt);
        scanA_kernel<<<SCAN_NBLK, 1024, 0, stream>>>(cnt, basep, bsum);
        scanB_kernel<<<1, 128, 0, stream>>>(bsum, boff);
        scanC_kernel<<<(N_NODES + 255) / 256, 256, 0, stream>>>(cnt, basep, boff, cur);
        perm_kernel<<<2048, 256, 0, stream>>>(eidx, cur, elist);
        fused_kernel<<<N_NODES / NPB, 512, 0, stream>>>(
            xb, ef, basep, elist, w1p, w2p, wn1p, wn2p,
            be1, be2, bn1, bn2, out);
    } else {
        hipMemsetAsync(d_out, 0, (size_t)N_NODES * 64 * sizeof(float), stream);
        edge_kernel_fb<<<1024, 256, 0, stream>>>(xb, eidx, ef, We1, be1, We2, be2, out);
        node_kernel_fb<<<(N_NODES + 63) / 64, 256, 0, stream>>>(x, Wn1, bn1, Wn2, bn2, out);
    }
}

// Round 7
// 975.226 us; speedup vs baseline: 1.0260x; 1.0260x over previous
//
#include <hip/hip_runtime.h>
#include <hip/hip_bf16.h>

#define N_NODES 100000
#define N_EDGES 1600000
#define NPB 32               // nodes per fused block (100000 = 32*3125 exactly)

typedef short s8v __attribute__((ext_vector_type(8)));
typedef float f4v __attribute__((ext_vector_type(4)));
typedef unsigned short us4 __attribute__((ext_vector_type(4)));

__device__ inline unsigned short f2bfn(float f) {
    __hip_bfloat16 h = __float2bfloat16(f);
    unsigned short u;
    __builtin_memcpy(&u, &h, 2);
    return u;
}

__device__ inline float silu_f(float v) {
    return v * __builtin_amdgcn_rcpf(1.0f + __expf(-v));
}

__device__ inline f4v splat4(float v) {
    f4v r;
    r[0] = v; r[1] = v; r[2] = v; r[3] = v;
    return r;
}

// ---------------------------------------------------------------------------
// Prepass: x (f32, [N,64]) -> bf16 copy in workspace.
// ---------------------------------------------------------------------------
__global__ __launch_bounds__(256) void x2bf_kernel(const float* __restrict__ x,
                                                   unsigned short* __restrict__ xb)
{
    const int total = N_NODES * 64 / 4;
    for (int i = blockIdx.x * blockDim.x + threadIdx.x; i < total;
         i += gridDim.x * blockDim.x) {
        f4v v = *(const f4v*)(x + (size_t)i * 4);
        us4 o;
        #pragma unroll
        for (int q = 0; q < 4; ++q) o[q] = f2bfn(v[q]);
        *(us4*)(xb + (size_t)i * 4) = o;
    }
}

// ---------------------------------------------------------------------------
// Weight prep: fragment-ordered bf16 copies (done once, tiny).
// ---------------------------------------------------------------------------
__global__ __launch_bounds__(256) void wprep_kernel(
    const float* __restrict__ We1, const float* __restrict__ We2,
    const float* __restrict__ Wn1, const float* __restrict__ Wn2,
    unsigned short* __restrict__ w1p, unsigned short* __restrict__ w2p,
    unsigned short* __restrict__ wn1p, unsigned short* __restrict__ wn2p)
{
    const int stride = gridDim.x * blockDim.x;
    const int tid0 = blockIdx.x * blockDim.x + threadIdx.x;
    for (int i = tid0; i < 64 * 160; i += stride) {
        int row = i / 160, k = i - row * 160;
        int t = row >> 4, lr = row & 15, s = k >> 5, kg = (k >> 3) & 3, j = k & 7;
        w1p[(((t * 5 + s) * 64) + (kg * 16 + lr)) * 8 + j] = f2bfn(We1[i]);
    }
    for (int i = tid0; i < 64 * 64; i += stride) {
        int row = i >> 6, k = i & 63;
        int t = row >> 4, lr = row & 15, s = k >> 5, kg = (k >> 3) & 3, j = k & 7;
        w2p[(((t * 2 + s) * 64) + (kg * 16 + lr)) * 8 + j] = f2bfn(We2[i]);
    }
    for (int i = tid0; i < 64 * 128; i += stride) {
        int row = i >> 7, k = i & 127;
        int t = row >> 4, lr = row & 15, s = k >> 5, kg = (k >> 3) & 3, j = k & 7;
        wn1p[(((t * 4 + s) * 64) + (kg * 16 + lr)) * 8 + j] = f2bfn(Wn1[i]);
    }
    for (int i = tid0; i < 64 * 64; i += stride) {
        int row = i >> 6, k = i & 63;
        int t = row >> 4, lr = row & 15, s = k >> 5, kg = (k >> 3) & 3, j = k & 7;
        wn2p[(((t * 2 + s) * 64) + (kg * 16 + lr)) * 8 + j] = f2bfn(Wn2[i]);
    }
}

// ---------------------------------------------------------------------------
// CSR build: histogram -> 2-level scan -> permutation
// ---------------------------------------------------------------------------
__global__ __launch_bounds__(256) void hist_kernel(const int* __restrict__ eidx,
                                                   int* cnt)
{
    for (int e = blockIdx.x * blockDim.x + threadIdx.x; e < N_EDGES;
         e += gridDim.x * blockDim.x)
        atomicAdd(&cnt[eidx[e]], 1);
}

#define SCAN_NBLK 98   // 98*1024 >= 100000

__global__ __launch_bounds__(1024) void scanA_kernel(const int* __restrict__ cnt,
                                                     int* base, int* bsum)
{
    __shared__ int sh[1024];
    const int t = threadIdx.x;
    const int i = blockIdx.x * 1024 + t;
    int c = (i < N_NODES) ? cnt[i] : 0;
    sh[t] = c;
    __syncthreads();
    for (int off = 1; off < 1024; off <<= 1) {
        int v = (t >= off) ? sh[t - off] : 0;
        __syncthreads();
        sh[t] += v;
        __syncthreads();
    }
    if (i < N_NODES) base[i] = sh[t];          // inclusive for now
    if (t == 1023) bsum[blockIdx.x] = sh[1023];
}

__global__ __launch_bounds__(128) void scanB_kernel(const int* __restrict__ bsum,
                                                    int* boff)
{
    __shared__ int sh[128];
    const int t = threadIdx.x;
    int v = (t < SCAN_NBLK) ? bsum[t] : 0;
    sh[t] = v;
    __syncthreads();
    for (int off = 1; off < 128; off <<= 1) {
        int u = (t >= off) ? sh[t - off] : 0;
        __syncthreads();
        sh[t] += u;
        __syncthreads();
    }
    boff[t] = sh[t] - v;   // exclusive
}

__global__ __launch_bounds__(256) void scanC_kernel(const int* __restrict__ cnt,
                                                    int* base, const int* __restrict__ boff,
                                                    int* cur)
{
    const int i = blockIdx.x * 256 + threadIdx.x;
    if (i < N_NODES) {
        int b = base[i] - cnt[i] + boff[i >> 10];   // exclusive prefix
        base[i] = b;
        cur[i]  = b;
    }
}

// elist entry: .x = e | rloc<<25  (e < 2^21, rloc 5b), .y = col
__global__ __launch_bounds__(256) void perm_kernel(const int* __restrict__ eidx,
                                                   int* cur, int2* __restrict__ elist)
{
    for (int e = blockIdx.x * blockDim.x + threadIdx.x; e < N_EDGES;
         e += gridDim.x * blockDim.x) {
        int r = eidx[e];
        int c = eidx[N_EDGES + e];
        int pos = atomicAdd(&cur[r], 1);
        elist[pos] = make_int2(e | ((r & (NPB - 1)) << 25), c);
    }
}

// ---------------------------------------------------------------------------
// Fused kernel: block = 32 nodes + all their edges.
// LDS: W1L 20480 + W2L 8192 + HL 16384 + AGG 8448 = 53504 B -> 3 blocks/CU.
// __launch_bounds__(512,4): round-6's (512,6) capped VGPR at 40 -> ~2GB of
// scratch spill traffic (WRITE_SIZE 825MB). (512,4) compiles to ~64 VGPR
// (round-4 evidence); 64 <= 512/6, so HW still co-schedules 3 blocks/CU.
// ---------------------------------------------------------------------------
__global__ __launch_bounds__(512, 4) void fused_kernel(
    const unsigned short* __restrict__ xb, const float* __restrict__ ef,
    const int* __restrict__ base, const int2* __restrict__ elist,
    const unsigned short* __restrict__ w1p, const unsigned short* __restrict__ w2p,
    const unsigned short* __restrict__ wn1p, const unsigned short* __restrict__ wn2p,
    const float* __restrict__ be1, const float* __restrict__ be2,
    const float* __restrict__ bn1, const float* __restrict__ bn2,
    float* __restrict__ out)
{
    __shared__ unsigned short W1L[20 * 64 * 8];    // 20480 B
    __shared__ unsigned short W2L[8 * 64 * 8];     //  8192 B
    __shared__ unsigned short HL[8][2][64][8];     // 16384 B
    __shared__ float AGG[NPB + 1][64];             //  8448 B (row NPB = trash)

    const int tid = threadIdx.x;

    // --- stage weights: pure vector copy (pre-formatted) + zero AGG ---
    {
        const s8v* s1 = (const s8v*)w1p;  s8v* d1 = (s8v*)W1L;
        for (int i = tid; i < 20 * 64; i += 512) d1[i] = s1[i];
        const s8v* s2 = (const s8v*)w2p;  s8v* d2 = (s8v*)W2L;
        for (int i = tid; i < 8 * 64; i += 512) d2[i] = s2[i];
    }
    for (int i = tid; i < (NPB + 1) * 64; i += 512) ((float*)AGG)[i] = 0.0f;
    __syncthreads();

    const int lane = tid & 63;
    const int wv   = tid >> 6;      // 0..7
    const int lrow = lane & 15;
    const int lkg  = lane >> 4;

    const int n0    = blockIdx.x * NPB;
    const int base0 = base[n0];
    // STRICT <: when n0+NPB == N_NODES, base[N_NODES] is OOB (aliases cur[0]).
    const int end   = (n0 + NPB < N_NODES) ? base[n0 + NPB] : N_EDGES;

    float b1f[4], b2f[4];
    #pragma unroll
    for (int t = 0; t < 4; ++t) {
        b1f[t] = be1[t * 16 + lrow];
        b2f[t] = be2[t * 16 + lrow];
    }

    // ---------------- edge phase (no barriers, waves independent) ----------
    int t0 = base0 + wv * 16;
    if (t0 < end) {
        int idx0 = t0 + lrow;
        int2 ent = elist[(idx0 < end) ? idx0 : base0];

        for (; t0 < end; t0 += 8 * 16) {
            const int  idx   = t0 + lrow;
            const bool valid = idx < end;
            const int ar    = valid ? (ent.x >> 25) : NPB;    // NPB = trash row
            const int e     = ent.x & 0x1FFFFFF;
            const int c     = ent.y;
            const int rowid = n0 + (ent.x >> 25);             // L1-hot (32 rows)

            // gather current A-fragments
            s8v afr[5];
            afr[0] = *(const s8v*)(xb + (size_t)rowid * 64 + lkg * 8);
            afr[1] = *(const s8v*)(xb + (size_t)rowid * 64 + 32 + lkg * 8);
            afr[2] = *(const s8v*)(xb + (size_t)c * 64 + lkg * 8);
            afr[3] = *(const s8v*)(xb + (size_t)c * 64 + 32 + lkg * 8);
            const float* ep = ef + (size_t)e * 32 + lkg * 8;
            f4v elo = *(const f4v*)ep;
            f4v ehi = *(const f4v*)(ep + 4);

            // prefetch next iteration's elist entry (hides one serial hop)
            const int tn = t0 + 8 * 16;
            if (tn < end) {
                int idxn = tn + lrow;
                ent = elist[(idxn < end) ? idxn : base0];
            }

            {
                s8v a4;
                #pragma unroll
                for (int q = 0; q < 4; ++q) {
                    a4[q]     = (short)f2bfn(elo[q]);
                    a4[q + 4] = (short)f2bfn(ehi[q]);
                }
                afr[4] = a4;
            }

            // GEMM1 [16,160] x [160,64]; bias folded into C-init
            f4v acc[4];
            #pragma unroll
            for (int t = 0; t < 4; ++t) acc[t] = splat4(b1f[t]);
            #pragma unroll
            for (int s = 0; s < 5; ++s) {
                #pragma unroll
                for (int t = 0; t < 4; ++t) {
                    s8v b = *(const s8v*)&W1L[((t * 5 + s) * 64 + lane) * 8];
                    acc[t] = __builtin_amdgcn_mfma_f32_16x16x32_bf16(afr[s], b, acc[t], 0, 0, 0);
                }
            }

            // silu -> HL (wave-private, fragment-major)
            #pragma unroll
            for (int t = 0; t < 4; ++t) {
                const int col = t * 16 + lrow;
                const int s = col >> 5, lsub = (col & 31) >> 3, j = col & 7;
                #pragma unroll
                for (int rr = 0; rr < 4; ++rr)
                    HL[wv][s][lsub * 16 + (lkg * 4 + rr)][j] = f2bfn(silu_f(acc[t][rr]));
            }

            // GEMM2 [16,64] x [64,64]; bias folded into C-init
            s8v h0 = *(const s8v*)&HL[wv][0][lane][0];
            s8v h1 = *(const s8v*)&HL[wv][1][lane][0];
            f4v c2[4];
            #pragma unroll
            for (int t = 0; t < 4; ++t) c2[t] = splat4(b2f[t]);
            #pragma unroll
            for (int t = 0; t < 4; ++t) {
                s8v b0 = *(const s8v*)&W2L[((t * 2 + 0) * 64 + lane) * 8];
                s8v b1 = *(const s8v*)&W2L[((t * 2 + 1) * 64 + lane) * 8];
                c2[t] = __builtin_amdgcn_mfma_f32_16x16x32_bf16(h0, b0, c2[t], 0, 0, 0);
                c2[t] = __builtin_amdgcn_mfma_f32_16x16x32_bf16(h1, b1, c2[t], 0, 0, 0);
            }

            // silu -> LDS segment-sum; tt=(t+lkg)&3 rotates the column group
            // per lane-quarter: 4-way same-bank collision -> 2-way (free).
            #pragma unroll
            for (int rr = 0; rr < 4; ++rr) {
                const int arb = __shfl(ar, lkg * 4 + rr);
                #pragma unroll
                for (int t = 0; t < 4; ++t) {
                    const int tt = (t + lkg) & 3;
                    atomicAdd(&AGG[arb][tt * 16 + lrow], silu_f(c2[tt][rr]));
                }
            }
        }
    }
    __syncthreads();

    // ---------------- node phase (waves 0..1, 16 rows each) ----------------
    if (wv < 2) {
        const int m0 = wv * 16;
        float n1f[4], n2f[4];
        #pragma unroll
        for (int t = 0; t < 4; ++t) {
            n1f[t] = bn1[t * 16 + lrow];
            n2f[t] = bn2[t * 16 + lrow];
        }

        const int n = n0 + m0 + lrow;   // 100000 % 32 == 0: no tail

        s8v a[4];
        a[0] = *(const s8v*)(xb + (size_t)n * 64 + lkg * 8);
        a[1] = *(const s8v*)(xb + (size_t)n * 64 + 32 + lkg * 8);
        #pragma unroll
        for (int s = 0; s < 2; ++s) {
            f4v g0 = *(const f4v*)&AGG[m0 + lrow][s * 32 + lkg * 8];
            f4v g1 = *(const f4v*)&AGG[m0 + lrow][s * 32 + lkg * 8 + 4];
            s8v av;
            #pragma unroll
            for (int q = 0; q < 4; ++q) {
                av[q]     = (short)f2bfn(g0[q]);
                av[q + 4] = (short)f2bfn(g1[q]);
            }
            a[2 + s] = av;
        }

        // GEMM1 [16,128] x [128,64]; B-frags straight from global (L2-hot)
        f4v acc[4];
        #pragma unroll
        for (int t = 0; t < 4; ++t) acc[t] = splat4(n1f[t]);
        #pragma unroll
        for (int s = 0; s < 4; ++s) {
            #pragma unroll
            for (int t = 0; t < 4; ++t) {
                s8v b = ((const s8v*)wn1p)[(t * 4 + s) * 64 + lane];
                acc[t] = __builtin_amdgcn_mfma_f32_16x16x32_bf16(a[s], b, acc[t], 0, 0, 0);
            }
        }

        #pragma unroll
        for (int t = 0; t < 4; ++t) {
            const int col = t * 16 + lrow;
            const int s = col >> 5, lsub = (col & 31) >> 3, j = col & 7;
            #pragma unroll
            for (int rr = 0; rr < 4; ++rr)
                HL[wv][s][lsub * 16 + (lkg * 4 + rr)][j] = f2bfn(silu_f(acc[t][rr]));
        }

        s8v h0 = *(const s8v*)&HL[wv][0][lane][0];
        s8v h1 = *(const s8v*)&HL[wv][1][lane][0];
        f4v c2[4];
        #pragma unroll
        for (int t = 0; t < 4; ++t) c2[t] = splat4(n2f[t]);
        #pragma unroll
        for (int t = 0; t < 4; ++t) {
            s8v b0 = ((const s8v*)wn2p)[(t * 2 + 0) * 64 + lane];
            s8v b1 = ((const s8v*)wn2p)[(t * 2 + 1) * 64 + lane];
            c2[t] = __builtin_amdgcn_mfma_f32_16x16x32_bf16(h0, b0, c2[t], 0, 0, 0);
            c2[t] = __builtin_amdgcn_mfma_f32_16x16x32_bf16(h1, b1, c2[t], 0, 0, 0);
        }

        #pragma unroll
        for (int rr = 0; rr < 4; ++rr) {
            float* dst = out + (size_t)(n0 + m0 + lkg * 4 + rr) * 64;
            #pragma unroll
            for (int t = 0; t < 4; ++t)
                dst[t * 16 + lrow] = c2[t][rr];
        }
    }
}

// ---------------------------------------------------------------------------
// Fallback (round-2 path) if ws is too small.
// ---------------------------------------------------------------------------
__global__ __launch_bounds__(256, 4) void edge_kernel_fb(
    const unsigned short* __restrict__ xb, const int* __restrict__ eidx,
    const float* __restrict__ ef,
    const float* __restrict__ We1, const float* __restrict__ be1,
    const float* __restrict__ We2, const float* __restrict__ be2,
    float* agg)
{
    __shared__ unsigned short W1L[64 * 160];
    __shared__ unsigned short W2L[64 * 64];
    __shared__ unsigned short HL[4][2][64][8];

    const int tid = threadIdx.x;
    for (int i = tid; i < 64 * 160; i += 256) {
        int row = i / 160, k = i - row * 160;
        int t = row >> 4, lr = row & 15, s = k >> 5, kg = (k >> 3) & 3, j = k & 7;
        W1L[(((t * 5 + s) * 64) + (kg * 16 + lr)) * 8 + j] = f2bfn(We1[i]);
    }
    for (int i = tid; i < 64 * 64; i += 256) {
        int row = i >> 6, k = i & 63;
        int t = row >> 4, lr = row & 15, s = k >> 5, kg = (k >> 3) & 3, j = k & 7;
        W2L[(((t * 2 + s) * 64) + (kg * 16 + lr)) * 8 + j] = f2bfn(We2[i]);
    }
    __syncthreads();

    const int lane = tid & 63, wv = tid >> 6, lrow = lane & 15, lkg = lane >> 4;
    float b1f[4], b2f[4];
    #pragma unroll
    for (int t = 0; t < 4; ++t) { b1f[t] = be1[t*16+lrow]; b2f[t] = be2[t*16+lrow]; }

    const int wave_id = blockIdx.x * 4 + wv, n_waves = gridDim.x * 4;
    for (int grp = wave_id; grp < N_EDGES / 16; grp += n_waves) {
        const int e0 = grp * 16;
        const int r = eidx[e0 + lrow];
        const int c = eidx[N_EDGES + e0 + lrow];
        s8v afr[5];
        afr[0] = *(const s8v*)(xb + (size_t)r * 64 + lkg * 8);
        afr[1] = *(const s8v*)(xb + (size_t)r * 64 + 32 + lkg * 8);
        afr[2] = *(const s8v*)(xb + (size_t)c * 64 + lkg * 8);
        afr[3] = *(const s8v*)(xb + (size_t)c * 64 + 32 + lkg * 8);
        {
            const float* ep = ef + (size_t)(e0 + lrow) * 32 + lkg * 8;
            f4v elo = *(const f4v*)ep, ehi = *(const f4v*)(ep + 4);
            s8v a4;
            #pragma unroll
            for (int q = 0; q < 4; ++q) { a4[q] = (short)f2bfn(elo[q]); a4[q+4] = (short)f2bfn(ehi[q]); }
            afr[4] = a4;
        }
        f4v acc[4];
        #pragma unroll
        for (int t = 0; t < 4; ++t) acc[t] = splat4(b1f[t]);
        #pragma unroll
        for (int s = 0; s < 5; ++s)
            #pragma unroll
            for (int t = 0; t < 4; ++t) {
                s8v b = *(const s8v*)&W1L[((t * 5 + s) * 64 + lane) * 8];
                acc[t] = __builtin_amdgcn_mfma_f32_16x16x32_bf16(afr[s], b, acc[t], 0, 0, 0);
            }
        #pragma unroll
        for (int t = 0; t < 4; ++t) {
            const int col = t*16+lrow, s = col >> 5, lsub = (col & 31) >> 3, j = col & 7;
            #pragma unroll
            for (int rr = 0; rr < 4; ++rr)
                HL[wv][s][lsub*16 + (lkg*4+rr)][j] = f2bfn(silu_f(acc[t][rr]));
        }
        s8v h0 = *(const s8v*)&HL[wv][0][lane][0];
        s8v h1 = *(const s8v*)&HL[wv][1][lane][0];
        f4v c2[4];
        #pragma unroll
        for (int t = 0; t < 4; ++t) c2[t] = splat4(b2f[t]);
        #pragma unroll
        for (int t = 0; t < 4; ++t) {
            s8v b0 = *(const s8v*)&W2L[((t*2+0)*64+lane)*8];
            s8v b1 = *(const s8v*)&W2L[((t*2+1)*64+lane)*8];
            c2[t] = __builtin_amdgcn_mfma_f32_16x16x32_bf16(h0, b0, c2[t], 0, 0, 0);
            c2[t] = __builtin_amdgcn_mfma_f32_16x16x32_bf16(h1, b1, c2[t], 0, 0, 0);
        }
        #pragma unroll
        for (int rr = 0; rr < 4; ++rr) {
            const int node = __shfl(r, lkg * 4 + rr);
            float* dst = agg + (size_t)node * 64;
            #pragma unroll
            for (int t = 0; t < 4; ++t)
                atomicAdd(dst + t * 16 + lrow, silu_f(c2[t][rr]));
        }
    }
}

__global__ __launch_bounds__(256) void node_kernel_fb(
    const float* __restrict__ x,
    const float* __restrict__ Wn1, const float* __restrict__ bn1,
    const float* __restrict__ Wn2, const float* __restrict__ bn2,
    float* io)
{
    __shared__ unsigned short A[64][136];
    __shared__ unsigned short W1[64][136];
    __shared__ unsigned short H[64][72];
    __shared__ unsigned short W2[64][72];
    __shared__ float B1[64];
    __shared__ float B2[64];

    const int tid = threadIdx.x;
    for (int i = tid; i < 64 * 128; i += 256) W1[i >> 7][i & 127] = f2bfn(Wn1[i]);
    for (int i = tid; i < 64 * 64; i += 256) W2[i >> 6][i & 63] = f2bfn(Wn2[i]);
    if (tid < 64) { B1[tid] = bn1[tid]; B2[tid] = bn2[tid]; }

    const int n0 = blockIdx.x * 64, g = tid >> 4, l16 = tid & 15;
    #pragma unroll
    for (int i = 0; i < 4; ++i) {
        int e = g + i * 16, n = n0 + e;
        if (n >= N_NODES) n = N_NODES - 1;
        f4v xv = *(const f4v*)(x + (size_t)n * 64 + l16 * 4);
        us4 av;
        #pragma unroll
        for (int q = 0; q < 4; ++q) av[q] = f2bfn(xv[q]);
        *(us4*)&A[e][l16 * 4] = av;
        f4v gv = *(const f4v*)(io + (size_t)n * 64 + l16 * 4);
        us4 ag;
        #pragma unroll
        for (int q = 0; q < 4; ++q) ag[q] = f2bfn(gv[q]);
        *(us4*)&A[e][64 + l16 * 4] = ag;
    }
    __syncthreads();

    const int lane = tid & 63, m0 = (tid >> 6) * 16, lrow = lane & 15, lkg = lane >> 4;
    f4v a0 = 0, a1 = 0, a2 = 0, a3 = 0;
    #pragma unroll
    for (int s = 0; s < 4; ++s) {
        int k0 = s * 32 + lkg * 8;
        s8v av = *(const s8v*)&A[m0 + lrow][k0];
        a0 = __builtin_amdgcn_mfma_f32_16x16x32_bf16(av, *(const s8v*)&W1[ 0+lrow][k0], a0, 0, 0, 0);
        a1 = __builtin_amdgcn_mfma_f32_16x16x32_bf16(av, *(const s8v*)&W1[16+lrow][k0], a1, 0, 0, 0);
        a2 = __builtin_amdgcn_mfma_f32_16x16x32_bf16(av, *(const s8v*)&W1[32+lrow][k0], a2, 0, 0, 0);
        a3 = __builtin_amdgcn_mfma_f32_16x16x32_bf16(av, *(const s8v*)&W1[48+lrow][k0], a3, 0, 0, 0);
    }
    {
        f4v accs[4] = {a0, a1, a2, a3};
        #pragma unroll
        for (int t = 0; t < 4; ++t) {
            int col = t * 16 + lrow;
            float bias = B1[col];
            #pragma unroll
            for (int r = 0; r < 4; ++r)
                H[m0 + lkg * 4 + r][col] = f2bfn(silu_f(accs[t][r] + bias));
        }
    }
    f4v c0 = 0, c1 = 0, c2 = 0, c3 = 0;
    #pragma unroll
    for (int s = 0; s < 2; ++s) {
        int k0 = s * 32 + lkg * 8;
        s8v av = *(const s8v*)&H[m0 + lrow][k0];
        c0 = __builtin_amdgcn_mfma_f32_16x16x32_bf16(av, *(const s8v*)&W2[ 0+lrow][k0], c0, 0, 0, 0);
        c1 = __builtin_amdgcn_mfma_f32_16x16x32_bf16(av, *(const s8v*)&W2[16+lrow][k0], c1, 0, 0, 0);
        c2 = __builtin_amdgcn_mfma_f32_16x16x32_bf16(av, *(const s8v*)&W2[32+lrow][k0], c2, 0, 0, 0);
        c3 = __builtin_amdgcn_mfma_f32_16x16x32_bf16(av, *(const s8v*)&W2[48+lrow][k0], c3, 0, 0, 0);
    }
    {
        f4v cs[4] = {c0, c1, c2, c3};
        #pragma unroll
        for (int r = 0; r < 4; ++r) {
            int n = n0 + m0 + lkg * 4 + r;
            if (n < N_NODES) {
                float* dst = io + (size_t)n * 64;
                #pragma unroll
                for (int t = 0; t < 4; ++t) dst[t * 16 + lrow] = cs[t][r] + B2[t * 16 + lrow];
            }
        }
    }
}

extern "C" void kernel_launch(void* const* d_in, const int* in_sizes, int n_in,
                              void* d_out, int out_size, void* d_ws, size_t ws_size,
                              hipStream_t stream) {
    const float* x    = (const float*)d_in[0];
    const int*   eidx = (const int*)  d_in[1];
    const float* ef   = (const float*)d_in[2];
    const float* We1  = (const float*)d_in[3];
    const float* be1  = (const float*)d_in[4];
    const float* We2  = (const float*)d_in[5];
    const float* be2  = (const float*)d_in[6];
    const float* Wn1  = (const float*)d_in[7];
    const float* bn1  = (const float*)d_in[8];
    const float* Wn2  = (const float*)d_in[9];
    const float* bn2  = (const float*)d_in[10];
    float* out = (float*)d_out;

    char* ws = (char*)d_ws;
    // ws layout (bytes)
    unsigned short* xb   = (unsigned short*)ws;                  // 12,800,000
    int*  cnt   = (int*) (ws + 12800000);                        //    400,000
    int*  basep = (int*) (ws + 13200000);                        //    400,000
    int*  cur   = (int*) (ws + 13600000);                        //    400,000
    int*  bsum  = (int*) (ws + 14000000);                        //        512
    int*  boff  = (int*) (ws + 14000512);                        //        512
    unsigned short* w1p  = (unsigned short*)(ws + 14001024);     //     20,480
    unsigned short* w2p  = (unsigned short*)(ws + 14021504);     //      8,192
    unsigned short* wn1p = (unsigned short*)(ws + 14029696);     //     16,384
    unsigned short* wn2p = (unsigned short*)(ws + 14046080);     //      8,192
    int2* elist = (int2*)(ws + 14054272);                        // 12,800,000
    const size_t WS_NEEDED = 26854272;

    x2bf_kernel<<<1024, 256, 0, stream>>>(x, xb);

    if (ws_size >= WS_NEEDED) {
        wprep_kernel<<<64, 256, 0, stream>>>(We1, We2, Wn1, Wn2, w1p, w2p, wn1p, wn2p);
        hipMemsetAsync(cnt, 0, N_NODES * sizeof(int), stream);
        hist_kernel<<<2048, 256, 0, stream>>>(eidx, cnt);
        scanA_kernel<<<SCAN_NBLK, 1024, 0, stream>>>(cnt, basep, bsum);
        scanB_kernel<<<1, 128, 0, stream>>>(bsum, boff);
        scanC_kernel<<<(N_NODES + 255) / 256, 256, 0, stream>>>(cnt, basep, boff, cur);
        perm_kernel<<<2048, 256, 0, stream>>>(eidx, cur, elist);
        fused_kernel<<<N_NODES / NPB, 512, 0, stream>>>(
            xb, ef, basep, elist, w1p, w2p, wn1p, wn2p,
            be1, be2, bn1, bn2, out);
    } else {
        hipMemsetAsync(d_out, 0, (size_t)N_NODES * 64 * sizeof(float), stream);
        edge_kernel_fb<<<1024, 256, 0, stream>>>(xb, eidx, ef, We1, be1, We2, be2, out);
        node_kernel_fb<<<(N_NODES + 63) / 64, 256, 0, stream>>>(x, Wn1, bn1, Wn2, bn2, out);
    }
}

// Round 8
// 905.732 us; speedup vs baseline: 1.1047x; 1.0767x over previous
//
#include <hip/hip_runtime.h>
#include <hip/hip_bf16.h>

#define N_NODES 100000
#define N_EDGES 1600000
#define NPB 32               // nodes per fused block (100000 = 32*3125 exactly)

typedef short s8v __attribute__((ext_vector_type(8)));
typedef float f4v __attribute__((ext_vector_type(4)));
typedef unsigned short us4 __attribute__((ext_vector_type(4)));

__device__ inline unsigned short f2bfn(float f) {
    __hip_bfloat16 h = __float2bfloat16(f);
    unsigned short u;
    __builtin_memcpy(&u, &h, 2);
    return u;
}

__device__ inline float silu_f(float v) {
    return v * __builtin_amdgcn_rcpf(1.0f + __expf(-v));
}

__device__ inline f4v splat4(float v) {
    f4v r;
    r[0] = v; r[1] = v; r[2] = v; r[3] = v;
    return r;
}

// ---------------------------------------------------------------------------
// Prepass: x (f32, [N,64]) -> bf16 copy in workspace.
// ---------------------------------------------------------------------------
__global__ __launch_bounds__(256) void x2bf_kernel(const float* __restrict__ x,
                                                   unsigned short* __restrict__ xb)
{
    const int total = N_NODES * 64 / 4;
    for (int i = blockIdx.x * blockDim.x + threadIdx.x; i < total;
         i += gridDim.x * blockDim.x) {
        f4v v = *(const f4v*)(x + (size_t)i * 4);
        us4 o;
        #pragma unroll
        for (int q = 0; q < 4; ++q) o[q] = f2bfn(v[q]);
        *(us4*)(xb + (size_t)i * 4) = o;
    }
}

// ---------------------------------------------------------------------------
// Weight prep: fragment-ordered bf16 copies (done once, tiny).
// ---------------------------------------------------------------------------
__global__ __launch_bounds__(256) void wprep_kernel(
    const float* __restrict__ We1, const float* __restrict__ We2,
    const float* __restrict__ Wn1, const float* __restrict__ Wn2,
    unsigned short* __restrict__ w1p, unsigned short* __restrict__ w2p,
    unsigned short* __restrict__ wn1p, unsigned short* __restrict__ wn2p)
{
    const int stride = gridDim.x * blockDim.x;
    const int tid0 = blockIdx.x * blockDim.x + threadIdx.x;
    for (int i = tid0; i < 64 * 160; i += stride) {
        int row = i / 160, k = i - row * 160;
        int t = row >> 4, lr = row & 15, s = k >> 5, kg = (k >> 3) & 3, j = k & 7;
        w1p[(((t * 5 + s) * 64) + (kg * 16 + lr)) * 8 + j] = f2bfn(We1[i]);
    }
    for (int i = tid0; i < 64 * 64; i += stride) {
        int row = i >> 6, k = i & 63;
        int t = row >> 4, lr = row & 15, s = k >> 5, kg = (k >> 3) & 3, j = k & 7;
        w2p[(((t * 2 + s) * 64) + (kg * 16 + lr)) * 8 + j] = f2bfn(We2[i]);
    }
    for (int i = tid0; i < 64 * 128; i += stride) {
        int row = i >> 7, k = i & 127;
        int t = row >> 4, lr = row & 15, s = k >> 5, kg = (k >> 3) & 3, j = k & 7;
        wn1p[(((t * 4 + s) * 64) + (kg * 16 + lr)) * 8 + j] = f2bfn(Wn1[i]);
    }
    for (int i = tid0; i < 64 * 64; i += stride) {
        int row = i >> 6, k = i & 63;
        int t = row >> 4, lr = row & 15, s = k >> 5, kg = (k >> 3) & 3, j = k & 7;
        wn2p[(((t * 2 + s) * 64) + (kg * 16 + lr)) * 8 + j] = f2bfn(Wn2[i]);
    }
}

// ---------------------------------------------------------------------------
// CSR build: histogram -> 2-level scan -> permutation
// ---------------------------------------------------------------------------
__global__ __launch_bounds__(256) void hist_kernel(const int* __restrict__ eidx,
                                                   int* cnt)
{
    for (int e = blockIdx.x * blockDim.x + threadIdx.x; e < N_EDGES;
         e += gridDim.x * blockDim.x)
        atomicAdd(&cnt[eidx[e]], 1);
}

#define SCAN_NBLK 98   // 98*1024 >= 100000

__global__ __launch_bounds__(1024) void scanA_kernel(const int* __restrict__ cnt,
                                                     int* base, int* bsum)
{
    __shared__ int sh[1024];
    const int t = threadIdx.x;
    const int i = blockIdx.x * 1024 + t;
    int c = (i < N_NODES) ? cnt[i] : 0;
    sh[t] = c;
    __syncthreads();
    for (int off = 1; off < 1024; off <<= 1) {
        int v = (t >= off) ? sh[t - off] : 0;
        __syncthreads();
        sh[t] += v;
        __syncthreads();
    }
    if (i < N_NODES) base[i] = sh[t];          // inclusive for now
    if (t == 1023) bsum[blockIdx.x] = sh[1023];
}

__global__ __launch_bounds__(128) void scanB_kernel(const int* __restrict__ bsum,
                                                    int* boff)
{
    __shared__ int sh[128];
    const int t = threadIdx.x;
    int v = (t < SCAN_NBLK) ? bsum[t] : 0;
    sh[t] = v;
    __syncthreads();
    for (int off = 1; off < 128; off <<= 1) {
        int u = (t >= off) ? sh[t - off] : 0;
        __syncthreads();
        sh[t] += u;
        __syncthreads();
    }
    boff[t] = sh[t] - v;   // exclusive
}

__global__ __launch_bounds__(256) void scanC_kernel(const int* __restrict__ cnt,
                                                    int* base, const int* __restrict__ boff,
                                                    int* cur)
{
    const int i = blockIdx.x * 256 + threadIdx.x;
    if (i < N_NODES) {
        int b = base[i] - cnt[i] + boff[i >> 10];   // exclusive prefix
        base[i] = b;
        cur[i]  = b;
    }
}

// elist entry: .x = e | rloc<<25  (e < 2^21, rloc 5b), .y = col
__global__ __launch_bounds__(256) void perm_kernel(const int* __restrict__ eidx,
                                                   int* cur, int2* __restrict__ elist)
{
    for (int e = blockIdx.x * blockDim.x + threadIdx.x; e < N_EDGES;
         e += gridDim.x * blockDim.x) {
        int r = eidx[e];
        int c = eidx[N_EDGES + e];
        int pos = atomicAdd(&cur[r], 1);
        elist[pos] = make_int2(e | ((r & (NPB - 1)) << 25), c);
    }
}

// ---------------------------------------------------------------------------
// Fused kernel: block = 32 nodes + all their edges.
// LDS: W1L 20480 + W2L 8192 + HL 16384 + AGG 8448 = 53504 B.
// 2-stage pipeline: elist entry prefetched 2 iters ahead, ef (the HBM/L3
// latency long pole) prefetched 1 iter ahead.  All register arrays are
// statically indexed (round-7's c2[runtime] caused 800MB scratch spill).
// ---------------------------------------------------------------------------
__global__ __launch_bounds__(512, 4) void fused_kernel(
    const unsigned short* __restrict__ xb, const float* __restrict__ ef,
    const int* __restrict__ base, const int2* __restrict__ elist,
    const unsigned short* __restrict__ w1p, const unsigned short* __restrict__ w2p,
    const unsigned short* __restrict__ wn1p, const unsigned short* __restrict__ wn2p,
    const float* __restrict__ be1, const float* __restrict__ be2,
    const float* __restrict__ bn1, const float* __restrict__ bn2,
    float* __restrict__ out)
{
    __shared__ unsigned short W1L[20 * 64 * 8];    // 20480 B
    __shared__ unsigned short W2L[8 * 64 * 8];     //  8192 B
    __shared__ unsigned short HL[8][2][64][8];     // 16384 B
    __shared__ float AGG[NPB + 1][64];             //  8448 B (row NPB = trash)

    const int tid = threadIdx.x;

    // --- stage weights: pure vector copy (pre-formatted) + zero AGG ---
    {
        const s8v* s1 = (const s8v*)w1p;  s8v* d1 = (s8v*)W1L;
        for (int i = tid; i < 20 * 64; i += 512) d1[i] = s1[i];
        const s8v* s2 = (const s8v*)w2p;  s8v* d2 = (s8v*)W2L;
        for (int i = tid; i < 8 * 64; i += 512) d2[i] = s2[i];
    }
    for (int i = tid; i < (NPB + 1) * 64; i += 512) ((float*)AGG)[i] = 0.0f;
    __syncthreads();

    const int lane = tid & 63;
    const int wv   = tid >> 6;      // 0..7
    const int lrow = lane & 15;
    const int lkg  = lane >> 4;

    const int n0    = blockIdx.x * NPB;
    const int base0 = base[n0];
    // STRICT <: when n0+NPB == N_NODES, base[N_NODES] is OOB (aliases cur[0]).
    const int end   = (n0 + NPB < N_NODES) ? base[n0 + NPB] : N_EDGES;

    float b1f[4], b2f[4];
    #pragma unroll
    for (int t = 0; t < 4; ++t) {
        b1f[t] = be1[t * 16 + lrow];
        b2f[t] = be2[t * 16 + lrow];
    }

    // ---------------- edge phase (no barriers, waves independent) ----------
    const int STEP = 8 * 16;
    int tC = base0 + wv * 16;
    if (tC < end) {
        // --- pipeline prologue ---
        int2 entC, entN;
        {
            int i0 = tC + lrow;
            entC = elist[(i0 < end) ? i0 : base0];
        }
        f4v eloC, ehiC;
        {
            const int e0 = entC.x & 0x1FFFFFF;
            const float* ep = ef + (size_t)e0 * 32 + lkg * 8;
            eloC = *(const f4v*)ep;
            ehiC = *(const f4v*)(ep + 4);
        }
        {
            int t1 = tC + STEP;
            int i1 = t1 + lrow;
            entN = (t1 < end) ? elist[(i1 < end) ? i1 : base0] : entC;
        }

        for (; tC < end; tC += STEP) {
            const bool valid = (tC + lrow) < end;
            const int  ar    = valid ? (entC.x >> 25) : NPB;  // NPB = trash row
            const int  c     = entC.y;
            const int  rowid = n0 + (entC.x >> 25);           // L1-hot (32 rows)

            // current xb gathers (row: L1-hot; col: L2/L3)
            s8v afr0 = *(const s8v*)(xb + (size_t)rowid * 64 + lkg * 8);
            s8v afr1 = *(const s8v*)(xb + (size_t)rowid * 64 + 32 + lkg * 8);
            s8v afr2 = *(const s8v*)(xb + (size_t)c * 64 + lkg * 8);
            s8v afr3 = *(const s8v*)(xb + (size_t)c * 64 + 32 + lkg * 8);

            // convert current ef (prefetched last iteration; arrived by now)
            s8v afr4;
            #pragma unroll
            for (int q = 0; q < 4; ++q) {
                afr4[q]     = (short)f2bfn(eloC[q]);
                afr4[q + 4] = (short)f2bfn(ehiC[q]);
            }

            // prefetch NEXT iteration's ef via entN (entry already in regs)
            if (tC + STEP < end) {
                const int en = entN.x & 0x1FFFFFF;
                const float* epn = ef + (size_t)en * 32 + lkg * 8;
                eloC = *(const f4v*)epn;
                ehiC = *(const f4v*)(epn + 4);
            }
            // rotate entries; load entry for i+2
            entC = entN;
            {
                int t2 = tC + 2 * STEP;
                if (t2 < end) {
                    int i2 = t2 + lrow;
                    entN = elist[(i2 < end) ? i2 : base0];
                }
            }

            // GEMM1 [16,160] x [160,64]; bias folded into C-init
            s8v afr[5] = {afr0, afr1, afr2, afr3, afr4};  // static-indexed
            f4v acc[4];
            #pragma unroll
            for (int t = 0; t < 4; ++t) acc[t] = splat4(b1f[t]);
            #pragma unroll
            for (int s = 0; s < 5; ++s) {
                #pragma unroll
                for (int t = 0; t < 4; ++t) {
                    s8v b = *(const s8v*)&W1L[((t * 5 + s) * 64 + lane) * 8];
                    acc[t] = __builtin_amdgcn_mfma_f32_16x16x32_bf16(afr[s], b, acc[t], 0, 0, 0);
                }
            }

            // silu -> HL (wave-private, fragment-major)
            #pragma unroll
            for (int t = 0; t < 4; ++t) {
                const int col = t * 16 + lrow;
                const int s = col >> 5, lsub = (col & 31) >> 3, j = col & 7;
                #pragma unroll
                for (int rr = 0; rr < 4; ++rr)
                    HL[wv][s][lsub * 16 + (lkg * 4 + rr)][j] = f2bfn(silu_f(acc[t][rr]));
            }

            // GEMM2 [16,64] x [64,64]; bias folded into C-init
            s8v h0 = *(const s8v*)&HL[wv][0][lane][0];
            s8v h1 = *(const s8v*)&HL[wv][1][lane][0];
            f4v c2[4];
            #pragma unroll
            for (int t = 0; t < 4; ++t) c2[t] = splat4(b2f[t]);
            #pragma unroll
            for (int t = 0; t < 4; ++t) {
                s8v b0 = *(const s8v*)&W2L[((t * 2 + 0) * 64 + lane) * 8];
                s8v b1 = *(const s8v*)&W2L[((t * 2 + 1) * 64 + lane) * 8];
                c2[t] = __builtin_amdgcn_mfma_f32_16x16x32_bf16(h0, b0, c2[t], 0, 0, 0);
                c2[t] = __builtin_amdgcn_mfma_f32_16x16x32_bf16(h1, b1, c2[t], 0, 0, 0);
            }

            // silu -> LDS segment-sum (STATIC t index — rule #20)
            #pragma unroll
            for (int rr = 0; rr < 4; ++rr) {
                const int arb = __shfl(ar, lkg * 4 + rr);
                #pragma unroll
                for (int t = 0; t < 4; ++t)
                    atomicAdd(&AGG[arb][t * 16 + lrow], silu_f(c2[t][rr]));
            }
        }
    }
    __syncthreads();

    // ---------------- node phase (waves 0..1, 16 rows each) ----------------
    if (wv < 2) {
        const int m0 = wv * 16;
        float n1f[4], n2f[4];
        #pragma unroll
        for (int t = 0; t < 4; ++t) {
            n1f[t] = bn1[t * 16 + lrow];
            n2f[t] = bn2[t * 16 + lrow];
        }

        const int n = n0 + m0 + lrow;   // 100000 % 32 == 0: no tail

        s8v a[4];
        a[0] = *(const s8v*)(xb + (size_t)n * 64 + lkg * 8);
        a[1] = *(const s8v*)(xb + (size_t)n * 64 + 32 + lkg * 8);
        #pragma unroll
        for (int s = 0; s < 2; ++s) {
            f4v g0 = *(const f4v*)&AGG[m0 + lrow][s * 32 + lkg * 8];
            f4v g1 = *(const f4v*)&AGG[m0 + lrow][s * 32 + lkg * 8 + 4];
            s8v av;
            #pragma unroll
            for (int q = 0; q < 4; ++q) {
                av[q]     = (short)f2bfn(g0[q]);
                av[q + 4] = (short)f2bfn(g1[q]);
            }
            a[2 + s] = av;
        }

        // GEMM1 [16,128] x [128,64]; B-frags straight from global (L2-hot)
        f4v acc[4];
        #pragma unroll
        for (int t = 0; t < 4; ++t) acc[t] = splat4(n1f[t]);
        #pragma unroll
        for (int s = 0; s < 4; ++s) {
            #pragma unroll
            for (int t = 0; t < 4; ++t) {
                s8v b = ((const s8v*)wn1p)[(t * 4 + s) * 64 + lane];
                acc[t] = __builtin_amdgcn_mfma_f32_16x16x32_bf16(a[s], b, acc[t], 0, 0, 0);
            }
        }

        #pragma unroll
        for (int t = 0; t < 4; ++t) {
            const int col = t * 16 + lrow;
            const int s = col >> 5, lsub = (col & 31) >> 3, j = col & 7;
            #pragma unroll
            for (int rr = 0; rr < 4; ++rr)
                HL[wv][s][lsub * 16 + (lkg * 4 + rr)][j] = f2bfn(silu_f(acc[t][rr]));
        }

        s8v h0 = *(const s8v*)&HL[wv][0][lane][0];
        s8v h1 = *(const s8v*)&HL[wv][1][lane][0];
        f4v c2[4];
        #pragma unroll
        for (int t = 0; t < 4; ++t) c2[t] = splat4(n2f[t]);
        #pragma unroll
        for (int t = 0; t < 4; ++t) {
            s8v b0 = ((const s8v*)wn2p)[(t * 2 + 0) * 64 + lane];
            s8v b1 = ((const s8v*)wn2p)[(t * 2 + 1) * 64 + lane];
            c2[t] = __builtin_amdgcn_mfma_f32_16x16x32_bf16(h0, b0, c2[t], 0, 0, 0);
            c2[t] = __builtin_amdgcn_mfma_f32_16x16x32_bf16(h1, b1, c2[t], 0, 0, 0);
        }

        #pragma unroll
        for (int rr = 0; rr < 4; ++rr) {
            float* dst = out + (size_t)(n0 + m0 + lkg * 4 + rr) * 64;
            #pragma unroll
            for (int t = 0; t < 4; ++t)
                dst[t * 16 + lrow] = c2[t][rr];
        }
    }
}

// ---------------------------------------------------------------------------
// Fallback (round-2 path) if ws is too small.
// ---------------------------------------------------------------------------
__global__ __launch_bounds__(256, 4) void edge_kernel_fb(
    const unsigned short* __restrict__ xb, const int* __restrict__ eidx,
    const float* __restrict__ ef,
    const float* __restrict__ We1, const float* __restrict__ be1,
    const float* __restrict__ We2, const float* __restrict__ be2,
    float* agg)
{
    __shared__ unsigned short W1L[64 * 160];
    __shared__ unsigned short W2L[64 * 64];
    __shared__ unsigned short HL[4][2][64][8];

    const int tid = threadIdx.x;
    for (int i = tid; i < 64 * 160; i += 256) {
        int row = i / 160, k = i - row * 160;
        int t = row >> 4, lr = row & 15, s = k >> 5, kg = (k >> 3) & 3, j = k & 7;
        W1L[(((t * 5 + s) * 64) + (kg * 16 + lr)) * 8 + j] = f2bfn(We1[i]);
    }
    for (int i = tid; i < 64 * 64; i += 256) {
        int row = i >> 6, k = i & 63;
        int t = row >> 4, lr = row & 15, s = k >> 5, kg = (k >> 3) & 3, j = k & 7;
        W2L[(((t * 2 + s) * 64) + (kg * 16 + lr)) * 8 + j] = f2bfn(We2[i]);
    }
    __syncthreads();

    const int lane = tid & 63, wv = tid >> 6, lrow = lane & 15, lkg = lane >> 4;
    float b1f[4], b2f[4];
    #pragma unroll
    for (int t = 0; t < 4; ++t) { b1f[t] = be1[t*16+lrow]; b2f[t] = be2[t*16+lrow]; }

    const int wave_id = blockIdx.x * 4 + wv, n_waves = gridDim.x * 4;
    for (int grp = wave_id; grp < N_EDGES / 16; grp += n_waves) {
        const int e0 = grp * 16;
        const int r = eidx[e0 + lrow];
        const int c = eidx[N_EDGES + e0 + lrow];
        s8v afr[5];
        afr[0] = *(const s8v*)(xb + (size_t)r * 64 + lkg * 8);
        afr[1] = *(const s8v*)(xb + (size_t)r * 64 + 32 + lkg * 8);
        afr[2] = *(const s8v*)(xb + (size_t)c * 64 + lkg * 8);
        afr[3] = *(const s8v*)(xb + (size_t)c * 64 + 32 + lkg * 8);
        {
            const float* ep = ef + (size_t)(e0 + lrow) * 32 + lkg * 8;
            f4v elo = *(const f4v*)ep, ehi = *(const f4v*)(ep + 4);
            s8v a4;
            #pragma unroll
            for (int q = 0; q < 4; ++q) { a4[q] = (short)f2bfn(elo[q]); a4[q+4] = (short)f2bfn(ehi[q]); }
            afr[4] = a4;
        }
        f4v acc[4];
        #pragma unroll
        for (int t = 0; t < 4; ++t) acc[t] = splat4(b1f[t]);
        #pragma unroll
        for (int s = 0; s < 5; ++s)
            #pragma unroll
            for (int t = 0; t < 4; ++t) {
                s8v b = *(const s8v*)&W1L[((t * 5 + s) * 64 + lane) * 8];
                acc[t] = __builtin_amdgcn_mfma_f32_16x16x32_bf16(afr[s], b, acc[t], 0, 0, 0);
            }
        #pragma unroll
        for (int t = 0; t < 4; ++t) {
            const int col = t*16+lrow, s = col >> 5, lsub = (col & 31) >> 3, j = col & 7;
            #pragma unroll
            for (int rr = 0; rr < 4; ++rr)
                HL[wv][s][lsub*16 + (lkg*4+rr)][j] = f2bfn(silu_f(acc[t][rr]));
        }
        s8v h0 = *(const s8v*)&HL[wv][0][lane][0];
        s8v h1 = *(const s8v*)&HL[wv][1][lane][0];
        f4v c2[4];
        #pragma unroll
        for (int t = 0; t < 4; ++t) c2[t] = splat4(b2f[t]);
        #pragma unroll
        for (int t = 0; t < 4; ++t) {
            s8v b0 = *(const s8v*)&W2L[((t*2+0)*64+lane)*8];
            s8v b1 = *(const s8v*)&W2L[((t*2+1)*64+lane)*8];
            c2[t] = __builtin_amdgcn_mfma_f32_16x16x32_bf16(h0, b0, c2[t], 0, 0, 0);
            c2[t] = __builtin_amdgcn_mfma_f32_16x16x32_bf16(h1, b1, c2[t], 0, 0, 0);
        }
        #pragma unroll
        for (int rr = 0; rr < 4; ++rr) {
            const int node = __shfl(r, lkg * 4 + rr);
            float* dst = agg + (size_t)node * 64;
            #pragma unroll
            for (int t = 0; t < 4; ++t)
                atomicAdd(dst + t * 16 + lrow, silu_f(c2[t][rr]));
        }
    }
}

__global__ __launch_bounds__(256) void node_kernel_fb(
    const float* __restrict__ x,
    const float* __restrict__ Wn1, const float* __restrict__ bn1,
    const float* __restrict__ Wn2, const float* __restrict__ bn2,
    float* io)
{
    __shared__ unsigned short A[64][136];
    __shared__ unsigned short W1[64][136];
    __shared__ unsigned short H[64][72];
    __shared__ unsigned short W2[64][72];
    __shared__ float B1[64];
    __shared__ float B2[64];

    const int tid = threadIdx.x;
    for (int i = tid; i < 64 * 128; i += 256) W1[i >> 7][i & 127] = f2bfn(Wn1[i]);
    for (int i = tid; i < 64 * 64; i += 256) W2[i >> 6][i & 63] = f2bfn(Wn2[i]);
    if (tid < 64) { B1[tid] = bn1[tid]; B2[tid] = bn2[tid]; }

    const int n0 = blockIdx.x * 64, g = tid >> 4, l16 = tid & 15;
    #pragma unroll
    for (int i = 0; i < 4; ++i) {
        int e = g + i * 16, n = n0 + e;
        if (n >= N_NODES) n = N_NODES - 1;
        f4v xv = *(const f4v*)(x + (size_t)n * 64 + l16 * 4);
        us4 av;
        #pragma unroll
        for (int q = 0; q < 4; ++q) av[q] = f2bfn(xv[q]);
        *(us4*)&A[e][l16 * 4] = av;
        f4v gv = *(const f4v*)(io + (size_t)n * 64 + l16 * 4);
        us4 ag;
        #pragma unroll
        for (int q = 0; q < 4; ++q) ag[q] = f2bfn(gv[q]);
        *(us4*)&A[e][64 + l16 * 4] = ag;
    }
    __syncthreads();

    const int lane = tid & 63, m0 = (tid >> 6) * 16, lrow = lane & 15, lkg = lane >> 4;
    f4v a0 = 0, a1 = 0, a2 = 0, a3 = 0;
    #pragma unroll
    for (int s = 0; s < 4; ++s) {
        int k0 = s * 32 + lkg * 8;
        s8v av = *(const s8v*)&A[m0 + lrow][k0];
        a0 = __builtin_amdgcn_mfma_f32_16x16x32_bf16(av, *(const s8v*)&W1[ 0+lrow][k0], a0, 0, 0, 0);
        a1 = __builtin_amdgcn_mfma_f32_16x16x32_bf16(av, *(const s8v*)&W1[16+lrow][k0], a1, 0, 0, 0);
        a2 = __builtin_amdgcn_mfma_f32_16x16x32_bf16(av, *(const s8v*)&W1[32+lrow][k0], a2, 0, 0, 0);
        a3 = __builtin_amdgcn_mfma_f32_16x16x32_bf16(av, *(const s8v*)&W1[48+lrow][k0], a3, 0, 0, 0);
    }
    {
        f4v accs[4] = {a0, a1, a2, a3};
        #pragma unroll
        for (int t = 0; t < 4; ++t) {
            int col = t * 16 + lrow;
            float bias = B1[col];
            #pragma unroll
            for (int r = 0; r < 4; ++r)
                H[m0 + lkg * 4 + r][col] = f2bfn(silu_f(accs[t][r] + bias));
        }
    }
    f4v c0 = 0, c1 = 0, c2 = 0, c3 = 0;
    #pragma unroll
    for (int s = 0; s < 2; ++s) {
        int k0 = s * 32 + lkg * 8;
        s8v av = *(const s8v*)&H[m0 + lrow][k0];
        c0 = __builtin_amdgcn_mfma_f32_16x16x32_bf16(av, *(const s8v*)&W2[ 0+lrow][k0], c0, 0, 0, 0);
        c1 = __builtin_amdgcn_mfma_f32_16x16x32_bf16(av, *(const s8v*)&W2[16+lrow][k0], c1, 0, 0, 0);
        c2 = __builtin_amdgcn_mfma_f32_16x16x32_bf16(av, *(const s8v*)&W2[32+lrow][k0], c2, 0, 0, 0);
        c3 = __builtin_amdgcn_mfma_f32_16x16x32_bf16(av, *(const s8v*)&W2[48+lrow][k0], c3, 0, 0, 0);
    }
    {
        f4v cs[4] = {c0, c1, c2, c3};
        #pragma unroll
        for (int r = 0; r < 4; ++r) {
            int n = n0 + m0 + lkg * 4 + r;
            if (n < N_NODES) {
                float* dst = io + (size_t)n * 64;
                #pragma unroll
                for (int t = 0; t < 4; ++t) dst[t * 16 + lrow] = cs[t][r] + B2[t * 16 + lrow];
            }
        }
    }
}

extern "C" void kernel_launch(void* const* d_in, const int* in_sizes, int n_in,
                              void* d_out, int out_size, void* d_ws, size_t ws_size,
                              hipStream_t stream) {
    const float* x    = (const float*)d_in[0];
    const int*   eidx = (const int*)  d_in[1];
    const float* ef   = (const float*)d_in[2];
    const float* We1  = (const float*)d_in[3];
    const float* be1  = (const float*)d_in[4];
    const float* We2  = (const float*)d_in[5];
    const float* be2  = (const float*)d_in[6];
    const float* Wn1  = (const float*)d_in[7];
    const float* bn1  = (const float*)d_in[8];
    const float* Wn2  = (const float*)d_in[9];
    const float* bn2  = (const float*)d_in[10];
    float* out = (float*)d_out;

    char* ws = (char*)d_ws;
    // ws layout (bytes)
    unsigned short* xb   = (unsigned short*)ws;                  // 12,800,000
    int*  cnt   = (int*) (ws + 12800000);                        //    400,000
    int*  basep = (int*) (ws + 13200000);                        //    400,000
    int*  cur   = (int*) (ws + 13600000);                        //    400,000
    int*  bsum  = (int*) (ws + 14000000);                        //        512
    int*  boff  = (int*) (ws + 14000512);                        //        512
    unsigned short* w1p  = (unsigned short*)(ws + 14001024);     //     20,480
    unsigned short* w2p  = (unsigned short*)(ws + 14021504);     //      8,192
    unsigned short* wn1p = (unsigned short*)(ws + 14029696);     //     16,384
    unsigned short* wn2p = (unsigned short*)(ws + 14046080);     //      8,192
    int2* elist = (int2*)(ws + 14054272);                        // 12,800,000
    const size_t WS_NEEDED = 26854272;

    x2bf_kernel<<<1024, 256, 0, stream>>>(x, xb);

    if (ws_size >= WS_NEEDED) {
        wprep_kernel<<<64, 256, 0, stream>>>(We1, We2, Wn1, Wn2, w1p, w2p, wn1p, wn2p);
        hipMemsetAsync(cnt, 0, N_NODES * sizeof(int), stream);
        hist_kernel<<<2048, 256, 0, stream>>>(eidx, cnt);
        scanA_kernel<<<SCAN_NBLK, 1024, 0, stream>>>(cnt, basep, bsum);
        scanB_kernel<<<1, 128, 0, stream>>>(bsum, boff);
        scanC_kernel<<<(N_NODES + 255) / 256, 256, 0, stream>>>(cnt, basep, boff, cur);
        perm_kernel<<<2048, 256, 0, stream>>>(eidx, cur, elist);
        fused_kernel<<<N_NODES / NPB, 512, 0, stream>>>(
            xb, ef, basep, elist, w1p, w2p, wn1p, wn2p,
            be1, be2, bn1, bn2, out);
    } else {
        hipMemsetAsync(d_out, 0, (size_t)N_NODES * 64 * sizeof(float), stream);
        edge_kernel_fb<<<1024, 256, 0, stream>>>(xb, eidx, ef, We1, be1, We2, be2, out);
        node_kernel_fb<<<(N_NODES + 63) / 64, 256, 0, stream>>>(x, Wn1, bn1, Wn2, bn2, out);
    }
}

// Round 9
// 888.232 us; speedup vs baseline: 1.1265x; 1.0197x over previous
//
#include <hip/hip_runtime.h>
#include <hip/hip_bf16.h>

#define N_NODES 100000
#define N_EDGES 1600000
#define NPB 64               // nodes per fused block; grid = 1563 (last block 32 nodes)

typedef short s8v __attribute__((ext_vector_type(8)));
typedef float f4v __attribute__((ext_vector_type(4)));
typedef unsigned short us4 __attribute__((ext_vector_type(4)));

__device__ inline unsigned short f2bfn(float f) {
    __hip_bfloat16 h = __float2bfloat16(f);
    unsigned short u;
    __builtin_memcpy(&u, &h, 2);
    return u;
}

__device__ inline float silu_f(float v) {
    return v * __builtin_amdgcn_rcpf(1.0f + __expf(-v));
}

__device__ inline f4v splat4(float v) {
    f4v r;
    r[0] = v; r[1] = v; r[2] = v; r[3] = v;
    return r;
}

// ---------------------------------------------------------------------------
// Prepass: x (f32, [N,64]) -> bf16 copy in workspace.
// ---------------------------------------------------------------------------
__global__ __launch_bounds__(256) void x2bf_kernel(const float* __restrict__ x,
                                                   unsigned short* __restrict__ xb)
{
    const int total = N_NODES * 64 / 4;
    for (int i = blockIdx.x * blockDim.x + threadIdx.x; i < total;
         i += gridDim.x * blockDim.x) {
        f4v v = *(const f4v*)(x + (size_t)i * 4);
        us4 o;
        #pragma unroll
        for (int q = 0; q < 4; ++q) o[q] = f2bfn(v[q]);
        *(us4*)(xb + (size_t)i * 4) = o;
    }
}

// ---------------------------------------------------------------------------
// Weight prep: fragment-ordered bf16 copies (done once, tiny).
// ---------------------------------------------------------------------------
__global__ __launch_bounds__(256) void wprep_kernel(
    const float* __restrict__ We1, const float* __restrict__ We2,
    const float* __restrict__ Wn1, const float* __restrict__ Wn2,
    unsigned short* __restrict__ w1p, unsigned short* __restrict__ w2p,
    unsigned short* __restrict__ wn1p, unsigned short* __restrict__ wn2p)
{
    const int stride = gridDim.x * blockDim.x;
    const int tid0 = blockIdx.x * blockDim.x + threadIdx.x;
    for (int i = tid0; i < 64 * 160; i += stride) {
        int row = i / 160, k = i - row * 160;
        int t = row >> 4, lr = row & 15, s = k >> 5, kg = (k >> 3) & 3, j = k & 7;
        w1p[(((t * 5 + s) * 64) + (kg * 16 + lr)) * 8 + j] = f2bfn(We1[i]);
    }
    for (int i = tid0; i < 64 * 64; i += stride) {
        int row = i >> 6, k = i & 63;
        int t = row >> 4, lr = row & 15, s = k >> 5, kg = (k >> 3) & 3, j = k & 7;
        w2p[(((t * 2 + s) * 64) + (kg * 16 + lr)) * 8 + j] = f2bfn(We2[i]);
    }
    for (int i = tid0; i < 64 * 128; i += stride) {
        int row = i >> 7, k = i & 127;
        int t = row >> 4, lr = row & 15, s = k >> 5, kg = (k >> 3) & 3, j = k & 7;
        wn1p[(((t * 4 + s) * 64) + (kg * 16 + lr)) * 8 + j] = f2bfn(Wn1[i]);
    }
    for (int i = tid0; i < 64 * 64; i += stride) {
        int row = i >> 6, k = i & 63;
        int t = row >> 4, lr = row & 15, s = k >> 5, kg = (k >> 3) & 3, j = k & 7;
        wn2p[(((t * 2 + s) * 64) + (kg * 16 + lr)) * 8 + j] = f2bfn(Wn2[i]);
    }
}

// ---------------------------------------------------------------------------
// CSR build: histogram -> 2-level scan -> permutation (elA + efp bf16)
// ---------------------------------------------------------------------------
__global__ __launch_bounds__(256) void hist_kernel(const int* __restrict__ eidx,
                                                   int* cnt)
{
    for (int e = blockIdx.x * blockDim.x + threadIdx.x; e < N_EDGES;
         e += gridDim.x * blockDim.x)
        atomicAdd(&cnt[eidx[e]], 1);
}

#define SCAN_NBLK 98   // 98*1024 >= 100000

__global__ __launch_bounds__(1024) void scanA_kernel(const int* __restrict__ cnt,
                                                     int* base, int* bsum)
{
    __shared__ int sh[1024];
    const int t = threadIdx.x;
    const int i = blockIdx.x * 1024 + t;
    int c = (i < N_NODES) ? cnt[i] : 0;
    sh[t] = c;
    __syncthreads();
    for (int off = 1; off < 1024; off <<= 1) {
        int v = (t >= off) ? sh[t - off] : 0;
        __syncthreads();
        sh[t] += v;
        __syncthreads();
    }
    if (i < N_NODES) base[i] = sh[t];          // inclusive for now
    if (t == 1023) bsum[blockIdx.x] = sh[1023];
}

__global__ __launch_bounds__(128) void scanB_kernel(const int* __restrict__ bsum,
                                                    int* boff)
{
    __shared__ int sh[128];
    const int t = threadIdx.x;
    int v = (t < SCAN_NBLK) ? bsum[t] : 0;
    sh[t] = v;
    __syncthreads();
    for (int off = 1; off < 128; off <<= 1) {
        int u = (t >= off) ? sh[t - off] : 0;
        __syncthreads();
        sh[t] += u;
        __syncthreads();
    }
    boff[t] = sh[t] - v;   // exclusive
}

__global__ __launch_bounds__(256) void scanC_kernel(const int* __restrict__ cnt,
                                                    int* base, const int* __restrict__ boff,
                                                    int* cur)
{
    const int i = blockIdx.x * 256 + threadIdx.x;
    if (i < N_NODES) {
        int b = base[i] - cnt[i] + boff[i >> 10];   // exclusive prefix
        base[i] = b;
        cur[i]  = b;
    }
}

// elA[pos] = col | rloc<<20  (col < 2^17, rloc < 2^7)
// efp[pos] = 32 bf16 edge features (coalesced full-sector 64B write)
__global__ __launch_bounds__(256) void perm_kernel(const int* __restrict__ eidx,
                                                   const float* __restrict__ ef,
                                                   int* cur, int* __restrict__ elA,
                                                   us4* __restrict__ efp)
{
    for (int e = blockIdx.x * blockDim.x + threadIdx.x; e < N_EDGES;
         e += gridDim.x * blockDim.x) {
        int r = eidx[e];
        int c = eidx[N_EDGES + e];
        int pos = atomicAdd(&cur[r], 1);
        elA[pos] = c | ((r & (NPB - 1)) << 20);
        const f4v* src = (const f4v*)(ef + (size_t)e * 32);
        us4* dst = efp + (size_t)pos * 8;
        #pragma unroll
        for (int q8 = 0; q8 < 8; ++q8) {
            f4v v = src[q8];
            us4 o;
            #pragma unroll
            for (int q = 0; q < 4; ++q) o[q] = f2bfn(v[q]);
            dst[q8] = o;
        }
    }
}

// ---------------------------------------------------------------------------
// Fused kernel: block = 64 nodes + all their edges.
// LDS: W1L 20480 + W2L 8192 + HL 16384 + AGG 65*68*4=17680 = 62736 B -> 2/CU.
// All fused-kernel global streams are coalesced (elA, efp) except the
// unavoidable xb[col] gather, which is prefetched one iteration ahead.
// Node weights staged into LDS once per block (saves ~110MB of L2 refetch).
// ---------------------------------------------------------------------------
__global__ __launch_bounds__(512, 4) void fused_kernel(
    const unsigned short* __restrict__ xb,
    const int* __restrict__ base, const int* __restrict__ elA,
    const unsigned short* __restrict__ efp,
    const unsigned short* __restrict__ w1p, const unsigned short* __restrict__ w2p,
    const unsigned short* __restrict__ wn1p, const unsigned short* __restrict__ wn2p,
    const float* __restrict__ be1, const float* __restrict__ be2,
    const float* __restrict__ bn1, const float* __restrict__ bn2,
    float* __restrict__ out)
{
    __shared__ unsigned short W1L[20 * 64 * 8];    // 20480 B (edge We1, later Wn1)
    __shared__ unsigned short W2L[8 * 64 * 8];     //  8192 B (edge We2, later Wn2)
    __shared__ unsigned short HL[8][2][64][8];     // 16384 B
    __shared__ float AGG[NPB + 1][68];             // 17680 B; stride 68 spreads banks

    const int tid = threadIdx.x;

    // --- stage edge weights (pure b128 copy, pre-formatted) + zero AGG ---
    {
        const s8v* s1 = (const s8v*)w1p;  s8v* d1 = (s8v*)W1L;
        for (int i = tid; i < 20 * 64; i += 512) d1[i] = s1[i];
        const s8v* s2 = (const s8v*)w2p;  s8v* d2 = (s8v*)W2L;
        for (int i = tid; i < 8 * 64; i += 512) d2[i] = s2[i];
    }
    for (int i = tid; i < (NPB + 1) * 68; i += 512) ((float*)AGG)[i] = 0.0f;
    __syncthreads();

    const int lane = tid & 63;
    const int wv   = tid >> 6;      // 0..7
    const int lrow = lane & 15;
    const int lkg  = lane >> 4;

    const int n0    = blockIdx.x * NPB;
    const int base0 = base[n0];
    // STRICT <: when n0+NPB >= N_NODES (last block), base[n0+NPB] is OOB.
    const int end   = (n0 + NPB < N_NODES) ? base[n0 + NPB] : N_EDGES;

    float b1f[4], b2f[4];
    #pragma unroll
    for (int t = 0; t < 4; ++t) {
        b1f[t] = be1[t * 16 + lrow];
        b2f[t] = be2[t * 16 + lrow];
    }

    // ---------------- edge phase (no barriers, waves independent) ----------
    const int STEP = 8 * 16;
    int tC = base0 + wv * 16;
    if (tC < end) {
        // prologue: entry + operands for iteration 0, entry for iteration 1
        int entC;
        s8v af2C, af3C, af4C;
        {
            int i0  = tC + lrow;
            int i0c = (i0 < end) ? i0 : base0;
            entC = elA[i0c];
            int c = entC & 0xFFFFF;
            af2C = *(const s8v*)(xb + (size_t)c * 64 + lkg * 8);
            af3C = *(const s8v*)(xb + (size_t)c * 64 + 32 + lkg * 8);
            af4C = *(const s8v*)(efp + (size_t)i0c * 32 + lkg * 8);
        }
        int entN = entC;
        {
            int t1 = tC + STEP;
            if (t1 < end) {
                int i1 = t1 + lrow;
                entN = elA[(i1 < end) ? i1 : base0];
            }
        }

        for (; tC < end; tC += STEP) {
            const bool valid = (tC + lrow) < end;
            const int  ar    = valid ? (entC >> 20) : NPB;    // NPB = trash row
            const int  rowid = n0 + (entC >> 20);             // L1-hot (64 rows)

            // row fragments (L1-hot, load now)
            s8v af0 = *(const s8v*)(xb + (size_t)rowid * 64 + lkg * 8);
            s8v af1 = *(const s8v*)(xb + (size_t)rowid * 64 + 32 + lkg * 8);

            // issue NEXT-iteration operand loads (col gather + efp stream)
            s8v af2N = af2C, af3N = af3C, af4N = af4C;
            {
                int tN = tC + STEP;
                if (tN < end) {
                    int iN  = tN + lrow;
                    int iNc = (iN < end) ? iN : base0;
                    int cN  = entN & 0xFFFFF;
                    af2N = *(const s8v*)(xb + (size_t)cN * 64 + lkg * 8);
                    af3N = *(const s8v*)(xb + (size_t)cN * 64 + 32 + lkg * 8);
                    af4N = *(const s8v*)(efp + (size_t)iNc * 32 + lkg * 8);
                }
            }
            int entN2 = entN;
            {
                int t2 = tC + 2 * STEP;
                if (t2 < end) {
                    int i2 = t2 + lrow;
                    entN2 = elA[(i2 < end) ? i2 : base0];
                }
            }

            // GEMM1 [16,160] x [160,64]; bias folded into C-init
            s8v afr[5] = {af0, af1, af2C, af3C, af4C};   // static-indexed
            f4v acc[4];
            #pragma unroll
            for (int t = 0; t < 4; ++t) acc[t] = splat4(b1f[t]);
            #pragma unroll
            for (int s = 0; s < 5; ++s) {
                #pragma unroll
                for (int t = 0; t < 4; ++t) {
                    s8v b = *(const s8v*)&W1L[((t * 5 + s) * 64 + lane) * 8];
                    acc[t] = __builtin_amdgcn_mfma_f32_16x16x32_bf16(afr[s], b, acc[t], 0, 0, 0);
                }
            }

            // silu -> HL (wave-private, fragment-major)
            #pragma unroll
            for (int t = 0; t < 4; ++t) {
                const int col = t * 16 + lrow;
                const int s = col >> 5, lsub = (col & 31) >> 3, j = col & 7;
                #pragma unroll
                for (int rr = 0; rr < 4; ++rr)
                    HL[wv][s][lsub * 16 + (lkg * 4 + rr)][j] = f2bfn(silu_f(acc[t][rr]));
            }

            // GEMM2 [16,64] x [64,64]; bias folded into C-init
            s8v h0 = *(const s8v*)&HL[wv][0][lane][0];
            s8v h1 = *(const s8v*)&HL[wv][1][lane][0];
            f4v c2[4];
            #pragma unroll
            for (int t = 0; t < 4; ++t) c2[t] = splat4(b2f[t]);
            #pragma unroll
            for (int t = 0; t < 4; ++t) {
                s8v b0 = *(const s8v*)&W2L[((t * 2 + 0) * 64 + lane) * 8];
                s8v b1 = *(const s8v*)&W2L[((t * 2 + 1) * 64 + lane) * 8];
                c2[t] = __builtin_amdgcn_mfma_f32_16x16x32_bf16(h0, b0, c2[t], 0, 0, 0);
                c2[t] = __builtin_amdgcn_mfma_f32_16x16x32_bf16(h1, b1, c2[t], 0, 0, 0);
            }

            // silu -> LDS segment-sum (static t index — rule #20)
            #pragma unroll
            for (int rr = 0; rr < 4; ++rr) {
                const int arb = __shfl(ar, lkg * 4 + rr);
                #pragma unroll
                for (int t = 0; t < 4; ++t)
                    atomicAdd(&AGG[arb][t * 16 + lrow], silu_f(c2[t][rr]));
            }

            // rotate pipeline registers
            entC = entN;  entN = entN2;
            af2C = af2N;  af3C = af3N;  af4C = af4N;
        }
    }
    __syncthreads();

    // --- restage node weights into LDS (one copy/block, not per-wave) ---
    {
        const s8v* s1 = (const s8v*)wn1p;  s8v* d1 = (s8v*)W1L;
        for (int i = tid; i < 16 * 64; i += 512) d1[i] = s1[i];
        const s8v* s2 = (const s8v*)wn2p;  s8v* d2 = (s8v*)W2L;
        for (int i = tid; i < 8 * 64; i += 512) d2[i] = s2[i];
    }
    __syncthreads();

    // ---------------- node phase (waves 0..3, 16 rows each) ----------------
    if (wv < 4) {
        const int m0 = wv * 16;
        float n1f[4], n2f[4];
        #pragma unroll
        for (int t = 0; t < 4; ++t) {
            n1f[t] = bn1[t * 16 + lrow];
            n2f[t] = bn2[t * 16 + lrow];
        }

        const int n  = n0 + m0 + lrow;
        const int nc = (n < N_NODES) ? n : (N_NODES - 1);   // last block tail

        s8v a[4];
        a[0] = *(const s8v*)(xb + (size_t)nc * 64 + lkg * 8);
        a[1] = *(const s8v*)(xb + (size_t)nc * 64 + 32 + lkg * 8);
        #pragma unroll
        for (int s = 0; s < 2; ++s) {
            f4v g0 = *(const f4v*)&AGG[m0 + lrow][s * 32 + lkg * 8];
            f4v g1 = *(const f4v*)&AGG[m0 + lrow][s * 32 + lkg * 8 + 4];
            s8v av;
            #pragma unroll
            for (int q = 0; q < 4; ++q) {
                av[q]     = (short)f2bfn(g0[q]);
                av[q + 4] = (short)f2bfn(g1[q]);
            }
            a[2 + s] = av;
        }

        // GEMM1 [16,128] x [128,64] from LDS
        f4v acc[4];
        #pragma unroll
        for (int t = 0; t < 4; ++t) acc[t] = splat4(n1f[t]);
        #pragma unroll
        for (int s = 0; s < 4; ++s) {
            #pragma unroll
            for (int t = 0; t < 4; ++t) {
                s8v b = *(const s8v*)&W1L[((t * 4 + s) * 64 + lane) * 8];
                acc[t] = __builtin_amdgcn_mfma_f32_16x16x32_bf16(a[s], b, acc[t], 0, 0, 0);
            }
        }

        #pragma unroll
        for (int t = 0; t < 4; ++t) {
            const int col = t * 16 + lrow;
            const int s = col >> 5, lsub = (col & 31) >> 3, j = col & 7;
            #pragma unroll
            for (int rr = 0; rr < 4; ++rr)
                HL[wv][s][lsub * 16 + (lkg * 4 + rr)][j] = f2bfn(silu_f(acc[t][rr]));
        }

        s8v h0 = *(const s8v*)&HL[wv][0][lane][0];
        s8v h1 = *(const s8v*)&HL[wv][1][lane][0];
        f4v c2[4];
        #pragma unroll
        for (int t = 0; t < 4; ++t) c2[t] = splat4(n2f[t]);
        #pragma unroll
        for (int t = 0; t < 4; ++t) {
            s8v b0 = *(const s8v*)&W2L[((t * 2 + 0) * 64 + lane) * 8];
            s8v b1 = *(const s8v*)&W2L[((t * 2 + 1) * 64 + lane) * 8];
            c2[t] = __builtin_amdgcn_mfma_f32_16x16x32_bf16(h0, b0, c2[t], 0, 0, 0);
            c2[t] = __builtin_amdgcn_mfma_f32_16x16x32_bf16(h1, b1, c2[t], 0, 0, 0);
        }

        #pragma unroll
        for (int rr = 0; rr < 4; ++rr) {
            const int nrow = n0 + m0 + lkg * 4 + rr;
            if (nrow < N_NODES) {
                float* dst = out + (size_t)nrow * 64;
                #pragma unroll
                for (int t = 0; t < 4; ++t)
                    dst[t * 16 + lrow] = c2[t][rr];
            }
        }
    }
}

// ---------------------------------------------------------------------------
// Fallback (round-2 path) if ws is too small.
// ---------------------------------------------------------------------------
__global__ __launch_bounds__(256, 4) void edge_kernel_fb(
    const unsigned short* __restrict__ xb, const int* __restrict__ eidx,
    const float* __restrict__ ef,
    const float* __restrict__ We1, const float* __restrict__ be1,
    const float* __restrict__ We2, const float* __restrict__ be2,
    float* agg)
{
    __shared__ unsigned short W1L[64 * 160];
    __shared__ unsigned short W2L[64 * 64];
    __shared__ unsigned short HL[4][2][64][8];

    const int tid = threadIdx.x;
    for (int i = tid; i < 64 * 160; i += 256) {
        int row = i / 160, k = i - row * 160;
        int t = row >> 4, lr = row & 15, s = k >> 5, kg = (k >> 3) & 3, j = k & 7;
        W1L[(((t * 5 + s) * 64) + (kg * 16 + lr)) * 8 + j] = f2bfn(We1[i]);
    }
    for (int i = tid; i < 64 * 64; i += 256) {
        int row = i >> 6, k = i & 63;
        int t = row >> 4, lr = row & 15, s = k >> 5, kg = (k >> 3) & 3, j = k & 7;
        W2L[(((t * 2 + s) * 64) + (kg * 16 + lr)) * 8 + j] = f2bfn(We2[i]);
    }
    __syncthreads();

    const int lane = tid & 63, wv = tid >> 6, lrow = lane & 15, lkg = lane >> 4;
    float b1f[4], b2f[4];
    #pragma unroll
    for (int t = 0; t < 4; ++t) { b1f[t] = be1[t*16+lrow]; b2f[t] = be2[t*16+lrow]; }

    const int wave_id = blockIdx.x * 4 + wv, n_waves = gridDim.x * 4;
    for (int grp = wave_id; grp < N_EDGES / 16; grp += n_waves) {
        const int e0 = grp * 16;
        const int r = eidx[e0 + lrow];
        const int c = eidx[N_EDGES + e0 + lrow];
        s8v afr[5];
        afr[0] = *(const s8v*)(xb + (size_t)r * 64 + lkg * 8);
        afr[1] = *(const s8v*)(xb + (size_t)r * 64 + 32 + lkg * 8);
        afr[2] = *(const s8v*)(xb + (size_t)c * 64 + lkg * 8);
        afr[3] = *(const s8v*)(xb + (size_t)c * 64 + 32 + lkg * 8);
        {
            const float* ep = ef + (size_t)(e0 + lrow) * 32 + lkg * 8;
            f4v elo = *(const f4v*)ep, ehi = *(const f4v*)(ep + 4);
            s8v a4;
            #pragma unroll
            for (int q = 0; q < 4; ++q) { a4[q] = (short)f2bfn(elo[q]); a4[q+4] = (short)f2bfn(ehi[q]); }
            afr[4] = a4;
        }
        f4v acc[4];
        #pragma unroll
        for (int t = 0; t < 4; ++t) acc[t] = splat4(b1f[t]);
        #pragma unroll
        for (int s = 0; s < 5; ++s)
            #pragma unroll
            for (int t = 0; t < 4; ++t) {
                s8v b = *(const s8v*)&W1L[((t * 5 + s) * 64 + lane) * 8];
                acc[t] = __builtin_amdgcn_mfma_f32_16x16x32_bf16(afr[s], b, acc[t], 0, 0, 0);
            }
        #pragma unroll
        for (int t = 0; t < 4; ++t) {
            const int col = t*16+lrow, s = col >> 5, lsub = (col & 31) >> 3, j = col & 7;
            #pragma unroll
            for (int rr = 0; rr < 4; ++rr)
                HL[wv][s][lsub*16 + (lkg*4+rr)][j] = f2bfn(silu_f(acc[t][rr]));
        }
        s8v h0 = *(const s8v*)&HL[wv][0][lane][0];
        s8v h1 = *(const s8v*)&HL[wv][1][lane][0];
        f4v c2[4];
        #pragma unroll
        for (int t = 0; t < 4; ++t) c2[t] = splat4(b2f[t]);
        #pragma unroll
        for (int t = 0; t < 4; ++t) {
            s8v b0 = *(const s8v*)&W2L[((t*2+0)*64+lane)*8];
            s8v b1 = *(const s8v*)&W2L[((t*2+1)*64+lane)*8];
            c2[t] = __builtin_amdgcn_mfma_f32_16x16x32_bf16(h0, b0, c2[t], 0, 0, 0);
            c2[t] = __builtin_amdgcn_mfma_f32_16x16x32_bf16(h1, b1, c2[t], 0, 0, 0);
        }
        #pragma unroll
        for (int rr = 0; rr < 4; ++rr) {
            const int node = __shfl(r, lkg * 4 + rr);
            float* dst = agg + (size_t)node * 64;
            #pragma unroll
            for (int t = 0; t < 4; ++t)
                atomicAdd(dst + t * 16 + lrow, silu_f(c2[t][rr]));
        }
    }
}

__global__ __launch_bounds__(256) void node_kernel_fb(
    const float* __restrict__ x,
    const float* __restrict__ Wn1, const float* __restrict__ bn1,
    const float* __restrict__ Wn2, const float* __restrict__ bn2,
    float* io)
{
    __shared__ unsigned short A[64][136];
    __shared__ unsigned short W1[64][136];
    __shared__ unsigned short H[64][72];
    __shared__ unsigned short W2[64][72];
    __shared__ float B1[64];
    __shared__ float B2[64];

    const int tid = threadIdx.x;
    for (int i = tid; i < 64 * 128; i += 256) W1[i >> 7][i & 127] = f2bfn(Wn1[i]);
    for (int i = tid; i < 64 * 64; i += 256) W2[i >> 6][i & 63] = f2bfn(Wn2[i]);
    if (tid < 64) { B1[tid] = bn1[tid]; B2[tid] = bn2[tid]; }

    const int n0 = blockIdx.x * 64, g = tid >> 4, l16 = tid & 15;
    #pragma unroll
    for (int i = 0; i < 4; ++i) {
        int e = g + i * 16, n = n0 + e;
        if (n >= N_NODES) n = N_NODES - 1;
        f4v xv = *(const f4v*)(x + (size_t)n * 64 + l16 * 4);
        us4 av;
        #pragma unroll
        for (int q = 0; q < 4; ++q) av[q] = f2bfn(xv[q]);
        *(us4*)&A[e][l16 * 4] = av;
        f4v gv = *(const f4v*)(io + (size_t)n * 64 + l16 * 4);
        us4 ag;
        #pragma unroll
        for (int q = 0; q < 4; ++q) ag[q] = f2bfn(gv[q]);
        *(us4*)&A[e][64 + l16 * 4] = ag;
    }
    __syncthreads();

    const int lane = tid & 63, m0 = (tid >> 6) * 16, lrow = lane & 15, lkg = lane >> 4;
    f4v a0 = 0, a1 = 0, a2 = 0, a3 = 0;
    #pragma unroll
    for (int s = 0; s < 4; ++s) {
        int k0 = s * 32 + lkg * 8;
        s8v av = *(const s8v*)&A[m0 + lrow][k0];
        a0 = __builtin_amdgcn_mfma_f32_16x16x32_bf16(av, *(const s8v*)&W1[ 0+lrow][k0], a0, 0, 0, 0);
        a1 = __builtin_amdgcn_mfma_f32_16x16x32_bf16(av, *(const s8v*)&W1[16+lrow][k0], a1, 0, 0, 0);
        a2 = __builtin_amdgcn_mfma_f32_16x16x32_bf16(av, *(const s8v*)&W1[32+lrow][k0], a2, 0, 0, 0);
        a3 = __builtin_amdgcn_mfma_f32_16x16x32_bf16(av, *(const s8v*)&W1[48+lrow][k0], a3, 0, 0, 0);
    }
    {
        f4v accs[4] = {a0, a1, a2, a3};
        #pragma unroll
        for (int t = 0; t < 4; ++t) {
            int col = t * 16 + lrow;
            float bias = B1[col];
            #pragma unroll
            for (int r = 0; r < 4; ++r)
                H[m0 + lkg * 4 + r][col] = f2bfn(silu_f(accs[t][r] + bias));
        }
    }
    f4v c0 = 0, c1 = 0, c2 = 0, c3 = 0;
    #pragma unroll
    for (int s = 0; s < 2; ++s) {
        int k0 = s * 32 + lkg * 8;
        s8v av = *(const s8v*)&H[m0 + lrow][k0];
        c0 = __builtin_amdgcn_mfma_f32_16x16x32_bf16(av, *(const s8v*)&W2[ 0+lrow][k0], c0, 0, 0, 0);
        c1 = __builtin_amdgcn_mfma_f32_16x16x32_bf16(av, *(const s8v*)&W2[16+lrow][k0], c1, 0, 0, 0);
        c2 = __builtin_amdgcn_mfma_f32_16x16x32_bf16(av, *(const s8v*)&W2[32+lrow][k0], c2, 0, 0, 0);
        c3 = __builtin_amdgcn_mfma_f32_16x16x32_bf16(av, *(const s8v*)&W2[48+lrow][k0], c3, 0, 0, 0);
    }
    {
        f4v cs[4] = {c0, c1, c2, c3};
        #pragma unroll
        for (int r = 0; r < 4; ++r) {
            int n = n0 + m0 + lkg * 4 + r;
            if (n < N_NODES) {
                float* dst = io + (size_t)n * 64;
                #pragma unroll
                for (int t = 0; t < 4; ++t) dst[t * 16 + lrow] = cs[t][r] + B2[t * 16 + lrow];
            }
        }
    }
}

extern "C" void kernel_launch(void* const* d_in, const int* in_sizes, int n_in,
                              void* d_out, int out_size, void* d_ws, size_t ws_size,
                              hipStream_t stream) {
    const float* x    = (const float*)d_in[0];
    const int*   eidx = (const int*)  d_in[1];
    const float* ef   = (const float*)d_in[2];
    const float* We1  = (const float*)d_in[3];
    const float* be1  = (const float*)d_in[4];
    const float* We2  = (const float*)d_in[5];
    const float* be2  = (const float*)d_in[6];
    const float* Wn1  = (const float*)d_in[7];
    const float* bn1  = (const float*)d_in[8];
    const float* Wn2  = (const float*)d_in[9];
    const float* bn2  = (const float*)d_in[10];
    float* out = (float*)d_out;

    char* ws = (char*)d_ws;
    // ws layout (bytes)
    unsigned short* xb   = (unsigned short*)ws;                  // 12,800,000
    int*  cnt   = (int*) (ws + 12800000);                        //    400,000
    int*  basep = (int*) (ws + 13200000);                        //    400,000
    int*  cur   = (int*) (ws + 13600000);                        //    400,000
    int*  bsum  = (int*) (ws + 14000000);                        //        512
    int*  boff  = (int*) (ws + 14000512);                        //        512
    unsigned short* w1p  = (unsigned short*)(ws + 14001024);     //     20,480
    unsigned short* w2p  = (unsigned short*)(ws + 14021504);     //      8,192
    unsigned short* wn1p = (unsigned short*)(ws + 14029696);     //     16,384
    unsigned short* wn2p = (unsigned short*)(ws + 14046080);     //      8,192
    int*  elA   = (int*) (ws + 14054272);                        //  6,400,000
    us4*  efp   = (us4*) (ws + 20454272);                        // 102,400,000
    const size_t WS_NEEDED = 122854272;

    x2bf_kernel<<<1024, 256, 0, stream>>>(x, xb);

    if (ws_size >= WS_NEEDED) {
        wprep_kernel<<<64, 256, 0, stream>>>(We1, We2, Wn1, Wn2, w1p, w2p, wn1p, wn2p);
        hipMemsetAsync(cnt, 0, N_NODES * sizeof(int), stream);
        hist_kernel<<<2048, 256, 0, stream>>>(eidx, cnt);
        scanA_kernel<<<SCAN_NBLK, 1024, 0, stream>>>(cnt, basep, bsum);
        scanB_kernel<<<1, 128, 0, stream>>>(bsum, boff);
        scanC_kernel<<<(N_NODES + 255) / 256, 256, 0, stream>>>(cnt, basep, boff, cur);
        perm_kernel<<<2048, 256, 0, stream>>>(eidx, ef, cur, elA, efp);
        fused_kernel<<<(N_NODES + NPB - 1) / NPB, 512, 0, stream>>>(
            xb, basep, elA, (const unsigned short*)efp,
            w1p, w2p, wn1p, wn2p, be1, be2, bn1, bn2, out);
    } else {
        hipMemsetAsync(d_out, 0, (size_t)N_NODES * 64 * sizeof(float), stream);
        edge_kernel_fb<<<1024, 256, 0, stream>>>(xb, eidx, ef, We1, be1, We2, be2, out);
        node_kernel_fb<<<(N_NODES + 63) / 64, 256, 0, stream>>>(x, Wn1, bn1, Wn2, bn2, out);
    }
}

// Round 10
// 854.618 us; speedup vs baseline: 1.1708x; 1.0393x over previous
//
#include <hip/hip_runtime.h>
#include <hip/hip_bf16.h>

#define N_NODES 100000
#define N_EDGES 1600000
#define NPB 64               // nodes per fused block; grid = 1563

typedef short s8v __attribute__((ext_vector_type(8)));
typedef float f4v __attribute__((ext_vector_type(4)));
typedef unsigned short us4 __attribute__((ext_vector_type(4)));

__device__ inline unsigned short f2bfn(float f) {
    __hip_bfloat16 h = __float2bfloat16(f);
    unsigned short u;
    __builtin_memcpy(&u, &h, 2);
    return u;
}

__device__ inline float silu_f(float v) {
    return v * __builtin_amdgcn_rcpf(1.0f + __expf(-v));
}

__device__ inline f4v splat4(float v) {
    f4v r;
    r[0] = v; r[1] = v; r[2] = v; r[3] = v;
    return r;
}

// ---------------------------------------------------------------------------
// Prepass: x (f32, [N,64]) -> bf16 copy in workspace.
// ---------------------------------------------------------------------------
__global__ __launch_bounds__(256) void x2bf_kernel(const float* __restrict__ x,
                                                   unsigned short* __restrict__ xb)
{
    const int total = N_NODES * 64 / 4;
    for (int i = blockIdx.x * blockDim.x + threadIdx.x; i < total;
         i += gridDim.x * blockDim.x) {
        f4v v = *(const f4v*)(x + (size_t)i * 4);
        us4 o;
        #pragma unroll
        for (int q = 0; q < 4; ++q) o[q] = f2bfn(v[q]);
        *(us4*)(xb + (size_t)i * 4) = o;
    }
}

// ---------------------------------------------------------------------------
// Weight prep: fragment-ordered bf16 copies (done once, tiny).
// ---------------------------------------------------------------------------
__global__ __launch_bounds__(256) void wprep_kernel(
    const float* __restrict__ We1, const float* __restrict__ We2,
    const float* __restrict__ Wn1, const float* __restrict__ Wn2,
    unsigned short* __restrict__ w1p, unsigned short* __restrict__ w2p,
    unsigned short* __restrict__ wn1p, unsigned short* __restrict__ wn2p)
{
    const int stride = gridDim.x * blockDim.x;
    const int tid0 = blockIdx.x * blockDim.x + threadIdx.x;
    for (int i = tid0; i < 64 * 160; i += stride) {
        int row = i / 160, k = i - row * 160;
        int t = row >> 4, lr = row & 15, s = k >> 5, kg = (k >> 3) & 3, j = k & 7;
        w1p[(((t * 5 + s) * 64) + (kg * 16 + lr)) * 8 + j] = f2bfn(We1[i]);
    }
    for (int i = tid0; i < 64 * 64; i += stride) {
        int row = i >> 6, k = i & 63;
        int t = row >> 4, lr = row & 15, s = k >> 5, kg = (k >> 3) & 3, j = k & 7;
        w2p[(((t * 2 + s) * 64) + (kg * 16 + lr)) * 8 + j] = f2bfn(We2[i]);
    }
    for (int i = tid0; i < 64 * 128; i += stride) {
        int row = i >> 7, k = i & 127;
        int t = row >> 4, lr = row & 15, s = k >> 5, kg = (k >> 3) & 3, j = k & 7;
        wn1p[(((t * 4 + s) * 64) + (kg * 16 + lr)) * 8 + j] = f2bfn(Wn1[i]);
    }
    for (int i = tid0; i < 64 * 64; i += stride) {
        int row = i >> 6, k = i & 63;
        int t = row >> 4, lr = row & 15, s = k >> 5, kg = (k >> 3) & 3, j = k & 7;
        wn2p[(((t * 2 + s) * 64) + (kg * 16 + lr)) * 8 + j] = f2bfn(Wn2[i]);
    }
}

// ---------------------------------------------------------------------------
// CSR build: histogram -> 2-level scan -> permutation (elA + efp bf16)
// ---------------------------------------------------------------------------
__global__ __launch_bounds__(256) void hist_kernel(const int* __restrict__ eidx,
                                                   int* cnt)
{
    for (int e = blockIdx.x * blockDim.x + threadIdx.x; e < N_EDGES;
         e += gridDim.x * blockDim.x)
        atomicAdd(&cnt[eidx[e]], 1);
}

#define SCAN_NBLK 98   // 98*1024 >= 100000

__global__ __launch_bounds__(1024) void scanA_kernel(const int* __restrict__ cnt,
                                                     int* base, int* bsum)
{
    __shared__ int sh[1024];
    const int t = threadIdx.x;
    const int i = blockIdx.x * 1024 + t;
    int c = (i < N_NODES) ? cnt[i] : 0;
    sh[t] = c;
    __syncthreads();
    for (int off = 1; off < 1024; off <<= 1) {
        int v = (t >= off) ? sh[t - off] : 0;
        __syncthreads();
        sh[t] += v;
        __syncthreads();
    }
    if (i < N_NODES) base[i] = sh[t];          // inclusive for now
    if (t == 1023) bsum[blockIdx.x] = sh[1023];
}

__global__ __launch_bounds__(128) void scanB_kernel(const int* __restrict__ bsum,
                                                    int* boff)
{
    __shared__ int sh[128];
    const int t = threadIdx.x;
    int v = (t < SCAN_NBLK) ? bsum[t] : 0;
    sh[t] = v;
    __syncthreads();
    for (int off = 1; off < 128; off <<= 1) {
        int u = (t >= off) ? sh[t - off] : 0;
        __syncthreads();
        sh[t] += u;
        __syncthreads();
    }
    boff[t] = sh[t] - v;   // exclusive
}

__global__ __launch_bounds__(256) void scanC_kernel(const int* __restrict__ cnt,
                                                    int* base, const int* __restrict__ boff,
                                                    int* cur)
{
    const int i = blockIdx.x * 256 + threadIdx.x;
    if (i < N_NODES) {
        int b = base[i] - cnt[i] + boff[i >> 10];   // exclusive prefix
        base[i] = b;
        cur[i]  = b;
    }
}

// elA[pos] = col | rloc<<20  (col < 2^17, rloc < 2^6)
// efp[pos] = 32 bf16 edge features (coalesced 64B read in fused kernel)
__global__ __launch_bounds__(256) void perm_kernel(const int* __restrict__ eidx,
                                                   const float* __restrict__ ef,
                                                   int* cur, int* __restrict__ elA,
                                                   us4* __restrict__ efp)
{
    for (int e = blockIdx.x * blockDim.x + threadIdx.x; e < N_EDGES;
         e += gridDim.x * blockDim.x) {
        int r = eidx[e];
        int c = eidx[N_EDGES + e];
        int pos = atomicAdd(&cur[r], 1);
        elA[pos] = c | ((r & (NPB - 1)) << 20);
        const f4v* src = (const f4v*)(ef + (size_t)e * 32);
        us4* dst = efp + (size_t)pos * 8;
        #pragma unroll
        for (int q8 = 0; q8 < 8; ++q8) {
            f4v v = src[q8];
            us4 o;
            #pragma unroll
            for (int q = 0; q < 4; ++q) o[q] = f2bfn(v[q]);
            dst[q8] = o;
        }
    }
}

// ---------------------------------------------------------------------------
// Fused kernel: block = 64 nodes + all their edges.
// LDS: W1L 20480 + W2L 8192 + HL 16384 + AGG 17680 + XROW 8192 = 70928 B.
//   -> 2 blocks/CU (LDS-capped); VGPR free up to 128.
// __launch_bounds__(512,2): gives the allocator 256-VGPR budget. Rounds 8/9
// spilled (~270MB scratch writes) with the allocator pinned at 64 VGPR.
// Block's 64 xb rows staged in XROW (XOR-swizzled chunks, T2) — removes all
// per-edge row refetch and serves the node phase.
// ---------------------------------------------------------------------------
__global__ __launch_bounds__(512, 2) void fused_kernel(
    const unsigned short* __restrict__ xb,
    const int* __restrict__ base, const int* __restrict__ elA,
    const unsigned short* __restrict__ efp,
    const unsigned short* __restrict__ w1p, const unsigned short* __restrict__ w2p,
    const unsigned short* __restrict__ wn1p, const unsigned short* __restrict__ wn2p,
    const float* __restrict__ be1, const float* __restrict__ be2,
    const float* __restrict__ bn1, const float* __restrict__ bn2,
    float* __restrict__ out)
{
    __shared__ unsigned short W1L[20 * 64 * 8];    // 20480 B (edge We1, later Wn1)
    __shared__ unsigned short W2L[8 * 64 * 8];     //  8192 B (edge We2, later Wn2)
    __shared__ unsigned short HL[8][2][64][8];     // 16384 B
    __shared__ float AGG[NPB + 1][68];             // 17680 B (stride 68)
    __shared__ unsigned short XROW[64 * 64];       //  8192 B (swizzled 16B chunks)

    const int tid = threadIdx.x;
    const int n0  = blockIdx.x * NPB;

    // --- stage weights (pure b128 copy) + block's x rows + zero AGG ---
    {
        const s8v* s1 = (const s8v*)w1p;  s8v* d1 = (s8v*)W1L;
        for (int i = tid; i < 20 * 64; i += 512) d1[i] = s1[i];
        const s8v* s2 = (const s8v*)w2p;  s8v* d2 = (s8v*)W2L;
        for (int i = tid; i < 8 * 64; i += 512) d2[i] = s2[i];
        // XROW: one 16B chunk per thread; chunk k of row stored at k^(row&7).
        // (reads may run past row N_NODES-1 on the last block: lands in ws
        //  scratch region, data unused)
        const int row = tid >> 3, k = tid & 7, kp = k ^ (row & 7);
        ((s8v*)XROW)[row * 8 + kp] =
            *(const s8v*)(xb + (size_t)(n0 + row) * 64 + k * 8);
    }
    for (int i = tid; i < (NPB + 1) * 68; i += 512) ((float*)AGG)[i] = 0.0f;
    __syncthreads();

    const int lane = tid & 63;
    const int wv   = tid >> 6;      // 0..7
    const int lrow = lane & 15;
    const int lkg  = lane >> 4;

    const int base0 = base[n0];
    // STRICT <: when n0+NPB >= N_NODES (last block), base[n0+NPB] is OOB.
    const int end   = (n0 + NPB < N_NODES) ? base[n0 + NPB] : N_EDGES;

    float b1f[4], b2f[4];
    #pragma unroll
    for (int t = 0; t < 4; ++t) {
        b1f[t] = be1[t * 16 + lrow];
        b2f[t] = be2[t * 16 + lrow];
    }

    // ---------------- edge phase (no barriers, waves independent) ----------
    const int STEP = 8 * 16;
    int tC = base0 + wv * 16;
    if (tC < end) {
        // prologue: entry + global operands for iter 0, entry for iter 1
        int entC;
        s8v af2C, af3C, af4C;
        {
            int i0  = tC + lrow;
            int i0c = (i0 < end) ? i0 : base0;
            entC = elA[i0c];
            int c = entC & 0xFFFFF;
            af2C = *(const s8v*)(xb + (size_t)c * 64 + lkg * 8);
            af3C = *(const s8v*)(xb + (size_t)c * 64 + 32 + lkg * 8);
            af4C = *(const s8v*)(efp + (size_t)i0c * 32 + lkg * 8);
        }
        int entN = entC;
        {
            int t1 = tC + STEP;
            if (t1 < end) {
                int i1 = t1 + lrow;
                entN = elA[(i1 < end) ? i1 : base0];
            }
        }

        for (; tC < end; tC += STEP) {
            const bool valid = (tC + lrow) < end;
            const int  arow  = entC >> 20;                    // 0..63 always
            const int  ar    = valid ? arow : NPB;            // NPB = trash row

            // row fragments from LDS (swizzled chunks)
            const int kp0 = lkg ^ (arow & 7);
            const int kp1 = (4 + lkg) ^ (arow & 7);
            s8v af0 = *(const s8v*)&XROW[arow * 64 + kp0 * 8];
            s8v af1 = *(const s8v*)&XROW[arow * 64 + kp1 * 8];

            // issue NEXT-iteration operand loads (col gather + efp stream)
            s8v af2N = af2C, af3N = af3C, af4N = af4C;
            {
                int tN = tC + STEP;
                if (tN < end) {
                    int iN  = tN + lrow;
                    int iNc = (iN < end) ? iN : base0;
                    int cN  = entN & 0xFFFFF;
                    af2N = *(const s8v*)(xb + (size_t)cN * 64 + lkg * 8);
                    af3N = *(const s8v*)(xb + (size_t)cN * 64 + 32 + lkg * 8);
                    af4N = *(const s8v*)(efp + (size_t)iNc * 32 + lkg * 8);
                }
            }
            int entN2 = entN;
            {
                int t2 = tC + 2 * STEP;
                if (t2 < end) {
                    int i2 = t2 + lrow;
                    entN2 = elA[(i2 < end) ? i2 : base0];
                }
            }

            // GEMM1 [16,160] x [160,64]; bias folded into C-init
            s8v afr[5] = {af0, af1, af2C, af3C, af4C};   // static-indexed
            f4v acc[4];
            #pragma unroll
            for (int t = 0; t < 4; ++t) acc[t] = splat4(b1f[t]);
            #pragma unroll
            for (int s = 0; s < 5; ++s) {
                #pragma unroll
                for (int t = 0; t < 4; ++t) {
                    s8v b = *(const s8v*)&W1L[((t * 5 + s) * 64 + lane) * 8];
                    acc[t] = __builtin_amdgcn_mfma_f32_16x16x32_bf16(afr[s], b, acc[t], 0, 0, 0);
                }
            }

            // silu -> HL (wave-private, fragment-major)
            #pragma unroll
            for (int t = 0; t < 4; ++t) {
                const int col = t * 16 + lrow;
                const int s = col >> 5, lsub = (col & 31) >> 3, j = col & 7;
                #pragma unroll
                for (int rr = 0; rr < 4; ++rr)
                    HL[wv][s][lsub * 16 + (lkg * 4 + rr)][j] = f2bfn(silu_f(acc[t][rr]));
            }

            // GEMM2 [16,64] x [64,64]; bias folded into C-init
            s8v h0 = *(const s8v*)&HL[wv][0][lane][0];
            s8v h1 = *(const s8v*)&HL[wv][1][lane][0];
            f4v c2[4];
            #pragma unroll
            for (int t = 0; t < 4; ++t) c2[t] = splat4(b2f[t]);
            #pragma unroll
            for (int t = 0; t < 4; ++t) {
                s8v b0 = *(const s8v*)&W2L[((t * 2 + 0) * 64 + lane) * 8];
                s8v b1 = *(const s8v*)&W2L[((t * 2 + 1) * 64 + lane) * 8];
                c2[t] = __builtin_amdgcn_mfma_f32_16x16x32_bf16(h0, b0, c2[t], 0, 0, 0);
                c2[t] = __builtin_amdgcn_mfma_f32_16x16x32_bf16(h1, b1, c2[t], 0, 0, 0);
            }

            // silu -> LDS segment-sum (static t index — rule #20)
            #pragma unroll
            for (int rr = 0; rr < 4; ++rr) {
                const int arb = __shfl(ar, lkg * 4 + rr);
                #pragma unroll
                for (int t = 0; t < 4; ++t)
                    atomicAdd(&AGG[arb][t * 16 + lrow], silu_f(c2[t][rr]));
            }

            // rotate pipeline registers
            entC = entN;  entN = entN2;
            af2C = af2N;  af3C = af3N;  af4C = af4N;
        }
    }
    __syncthreads();

    // --- restage node weights into LDS (one copy/block) ---
    {
        const s8v* s1 = (const s8v*)wn1p;  s8v* d1 = (s8v*)W1L;
        for (int i = tid; i < 16 * 64; i += 512) d1[i] = s1[i];
        const s8v* s2 = (const s8v*)wn2p;  s8v* d2 = (s8v*)W2L;
        for (int i = tid; i < 8 * 64; i += 512) d2[i] = s2[i];
    }
    __syncthreads();

    // ---------------- node phase (waves 0..3, 16 rows each) ----------------
    if (wv < 4) {
        const int m0 = wv * 16;
        float n1f[4], n2f[4];
        #pragma unroll
        for (int t = 0; t < 4; ++t) {
            n1f[t] = bn1[t * 16 + lrow];
            n2f[t] = bn2[t * 16 + lrow];
        }

        const int row = m0 + lrow;                      // block-local 0..63
        const int kq0 = lkg ^ (row & 7);
        const int kq1 = (4 + lkg) ^ (row & 7);

        s8v a[4];
        a[0] = *(const s8v*)&XROW[row * 64 + kq0 * 8];
        a[1] = *(const s8v*)&XROW[row * 64 + kq1 * 8];
        #pragma unroll
        for (int s = 0; s < 2; ++s) {
            f4v g0 = *(const f4v*)&AGG[row][s * 32 + lkg * 8];
            f4v g1 = *(const f4v*)&AGG[row][s * 32 + lkg * 8 + 4];
            s8v av;
            #pragma unroll
            for (int q = 0; q < 4; ++q) {
                av[q]     = (short)f2bfn(g0[q]);
                av[q + 4] = (short)f2bfn(g1[q]);
            }
            a[2 + s] = av;
        }

        // GEMM1 [16,128] x [128,64] from LDS
        f4v acc[4];
        #pragma unroll
        for (int t = 0; t < 4; ++t) acc[t] = splat4(n1f[t]);
        #pragma unroll
        for (int s = 0; s < 4; ++s) {
            #pragma unroll
            for (int t = 0; t < 4; ++t) {
                s8v b = *(const s8v*)&W1L[((t * 4 + s) * 64 + lane) * 8];
                acc[t] = __builtin_amdgcn_mfma_f32_16x16x32_bf16(a[s], b, acc[t], 0, 0, 0);
            }
        }

        #pragma unroll
        for (int t = 0; t < 4; ++t) {
            const int col = t * 16 + lrow;
            const int s = col >> 5, lsub = (col & 31) >> 3, j = col & 7;
            #pragma unroll
            for (int rr = 0; rr < 4; ++rr)
                HL[wv][s][lsub * 16 + (lkg * 4 + rr)][j] = f2bfn(silu_f(acc[t][rr]));
        }

        s8v h0 = *(const s8v*)&HL[wv][0][lane][0];
        s8v h1 = *(const s8v*)&HL[wv][1][lane][0];
        f4v c2[4];
        #pragma unroll
        for (int t = 0; t < 4; ++t) c2[t] = splat4(n2f[t]);
        #pragma unroll
        for (int t = 0; t < 4; ++t) {
            s8v b0 = *(const s8v*)&W2L[((t * 2 + 0) * 64 + lane) * 8];
            s8v b1 = *(const s8v*)&W2L[((t * 2 + 1) * 64 + lane) * 8];
            c2[t] = __builtin_amdgcn_mfma_f32_16x16x32_bf16(h0, b0, c2[t], 0, 0, 0);
            c2[t] = __builtin_amdgcn_mfma_f32_16x16x32_bf16(h1, b1, c2[t], 0, 0, 0);
        }

        #pragma unroll
        for (int rr = 0; rr < 4; ++rr) {
            const int nrow = n0 + m0 + lkg * 4 + rr;
            if (nrow < N_NODES) {
                float* dst = out + (size_t)nrow * 64;
                #pragma unroll
                for (int t = 0; t < 4; ++t)
                    dst[t * 16 + lrow] = c2[t][rr];
            }
        }
    }
}

// ---------------------------------------------------------------------------
// Fallback (round-2 path) if ws is too small.
// ---------------------------------------------------------------------------
__global__ __launch_bounds__(256, 4) void edge_kernel_fb(
    const unsigned short* __restrict__ xb, const int* __restrict__ eidx,
    const float* __restrict__ ef,
    const float* __restrict__ We1, const float* __restrict__ be1,
    const float* __restrict__ We2, const float* __restrict__ be2,
    float* agg)
{
    __shared__ unsigned short W1L[64 * 160];
    __shared__ unsigned short W2L[64 * 64];
    __shared__ unsigned short HL[4][2][64][8];

    const int tid = threadIdx.x;
    for (int i = tid; i < 64 * 160; i += 256) {
        int row = i / 160, k = i - row * 160;
        int t = row >> 4, lr = row & 15, s = k >> 5, kg = (k >> 3) & 3, j = k & 7;
        W1L[(((t * 5 + s) * 64) + (kg * 16 + lr)) * 8 + j] = f2bfn(We1[i]);
    }
    for (int i = tid; i < 64 * 64; i += 256) {
        int row = i >> 6, k = i & 63;
        int t = row >> 4, lr = row & 15, s = k >> 5, kg = (k >> 3) & 3, j = k & 7;
        W2L[(((t * 2 + s) * 64) + (kg * 16 + lr)) * 8 + j] = f2bfn(We2[i]);
    }
    __syncthreads();

    const int lane = tid & 63, wv = tid >> 6, lrow = lane & 15, lkg = lane >> 4;
    float b1f[4], b2f[4];
    #pragma unroll
    for (int t = 0; t < 4; ++t) { b1f[t] = be1[t*16+lrow]; b2f[t] = be2[t*16+lrow]; }

    const int wave_id = blockIdx.x * 4 + wv, n_waves = gridDim.x * 4;
    for (int grp = wave_id; grp < N_EDGES / 16; grp += n_waves) {
        const int e0 = grp * 16;
        const int r = eidx[e0 + lrow];
        const int c = eidx[N_EDGES + e0 + lrow];
        s8v afr[5];
        afr[0] = *(const s8v*)(xb + (size_t)r * 64 + lkg * 8);
        afr[1] = *(const s8v*)(xb + (size_t)r * 64 + 32 + lkg * 8);
        afr[2] = *(const s8v*)(xb + (size_t)c * 64 + lkg * 8);
        afr[3] = *(const s8v*)(xb + (size_t)c * 64 + 32 + lkg * 8);
        {
            const float* ep = ef + (size_t)(e0 + lrow) * 32 + lkg * 8;
            f4v elo = *(const f4v*)ep, ehi = *(const f4v*)(ep + 4);
            s8v a4;
            #pragma unroll
            for (int q = 0; q < 4; ++q) { a4[q] = (short)f2bfn(elo[q]); a4[q+4] = (short)f2bfn(ehi[q]); }
            afr[4] = a4;
        }
        f4v acc[4];
        #pragma unroll
        for (int t = 0; t < 4; ++t) acc[t] = splat4(b1f[t]);
        #pragma unroll
        for (int s = 0; s < 5; ++s)
            #pragma unroll
            for (int t = 0; t < 4; ++t) {
                s8v b = *(const s8v*)&W1L[((t * 5 + s) * 64 + lane) * 8];
                acc[t] = __builtin_amdgcn_mfma_f32_16x16x32_bf16(afr[s], b, acc[t], 0, 0, 0);
            }
        #pragma unroll
        for (int t = 0; t < 4; ++t) {
            const int col = t*16+lrow, s = col >> 5, lsub = (col & 31) >> 3, j = col & 7;
            #pragma unroll
            for (int rr = 0; rr < 4; ++rr)
                HL[wv][s][lsub*16 + (lkg*4+rr)][j] = f2bfn(silu_f(acc[t][rr]));
        }
        s8v h0 = *(const s8v*)&HL[wv][0][lane][0];
        s8v h1 = *(const s8v*)&HL[wv][1][lane][0];
        f4v c2[4];
        #pragma unroll
        for (int t = 0; t < 4; ++t) c2[t] = splat4(b2f[t]);
        #pragma unroll
        for (int t = 0; t < 4; ++t) {
            s8v b0 = *(const s8v*)&W2L[((t*2+0)*64+lane)*8];
            s8v b1 = *(const s8v*)&W2L[((t*2+1)*64+lane)*8];
            c2[t] = __builtin_amdgcn_mfma_f32_16x16x32_bf16(h0, b0, c2[t], 0, 0, 0);
            c2[t] = __builtin_amdgcn_mfma_f32_16x16x32_bf16(h1, b1, c2[t], 0, 0, 0);
        }
        #pragma unroll
        for (int rr = 0; rr < 4; ++rr) {
            const int node = __shfl(r, lkg * 4 + rr);
            float* dst = agg + (size_t)node * 64;
            #pragma unroll
            for (int t = 0; t < 4; ++t)
                atomicAdd(dst + t * 16 + lrow, silu_f(c2[t][rr]));
        }
    }
}

__global__ __launch_bounds__(256) void node_kernel_fb(
    const float* __restrict__ x,
    const float* __restrict__ Wn1, const float* __restrict__ bn1,
    const float* __restrict__ Wn2, const float* __restrict__ bn2,
    float* io)
{
    __shared__ unsigned short A[64][136];
    __shared__ unsigned short W1[64][136];
    __shared__ unsigned short H[64][72];
    __shared__ unsigned short W2[64][72];
    __shared__ float B1[64];
    __shared__ float B2[64];

    const int tid = threadIdx.x;
    for (int i = tid; i < 64 * 128; i += 256) W1[i >> 7][i & 127] = f2bfn(Wn1[i]);
    for (int i = tid; i < 64 * 64; i += 256) W2[i >> 6][i & 63] = f2bfn(Wn2[i]);
    if (tid < 64) { B1[tid] = bn1[tid]; B2[tid] = bn2[tid]; }

    const int n0 = blockIdx.x * 64, g = tid >> 4, l16 = tid & 15;
    #pragma unroll
    for (int i = 0; i < 4; ++i) {
        int e = g + i * 16, n = n0 + e;
        if (n >= N_NODES) n = N_NODES - 1;
        f4v xv = *(const f4v*)(x + (size_t)n * 64 + l16 * 4);
        us4 av;
        #pragma unroll
        for (int q = 0; q < 4; ++q) av[q] = f2bfn(xv[q]);
        *(us4*)&A[e][l16 * 4] = av;
        f4v gv = *(const f4v*)(io + (size_t)n * 64 + l16 * 4);
        us4 ag;
        #pragma unroll
        for (int q = 0; q < 4; ++q) ag[q] = f2bfn(gv[q]);
        *(us4*)&A[e][64 + l16 * 4] = ag;
    }
    __syncthreads();

    const int lane = tid & 63, m0 = (tid >> 6) * 16, lrow = lane & 15, lkg = lane >> 4;
    f4v a0 = 0, a1 = 0, a2 = 0, a3 = 0;
    #pragma unroll
    for (int s = 0; s < 4; ++s) {
        int k0 = s * 32 + lkg * 8;
        s8v av = *(const s8v*)&A[m0 + lrow][k0];
        a0 = __builtin_amdgcn_mfma_f32_16x16x32_bf16(av, *(const s8v*)&W1[ 0+lrow][k0], a0, 0, 0, 0);
        a1 = __builtin_amdgcn_mfma_f32_16x16x32_bf16(av, *(const s8v*)&W1[16+lrow][k0], a1, 0, 0, 0);
        a2 = __builtin_amdgcn_mfma_f32_16x16x32_bf16(av, *(const s8v*)&W1[32+lrow][k0], a2, 0, 0, 0);
        a3 = __builtin_amdgcn_mfma_f32_16x16x32_bf16(av, *(const s8v*)&W1[48+lrow][k0], a3, 0, 0, 0);
    }
    {
        f4v accs[4] = {a0, a1, a2, a3};
        #pragma unroll
        for (int t = 0; t < 4; ++t) {
            int col = t * 16 + lrow;
            float bias = B1[col];
            #pragma unroll
            for (int r = 0; r < 4; ++r)
                H[m0 + lkg * 4 + r][col] = f2bfn(silu_f(accs[t][r] + bias));
        }
    }
    f4v c0 = 0, c1 = 0, c2 = 0, c3 = 0;
    #pragma unroll
    for (int s = 0; s < 2; ++s) {
        int k0 = s * 32 + lkg * 8;
        s8v av = *(const s8v*)&H[m0 + lrow][k0];
        c0 = __builtin_amdgcn_mfma_f32_16x16x32_bf16(av, *(const s8v*)&W2[ 0+lrow][k0], c0, 0, 0, 0);
        c1 = __builtin_amdgcn_mfma_f32_16x16x32_bf16(av, *(const s8v*)&W2[16+lrow][k0], c1, 0, 0, 0);
        c2 = __builtin_amdgcn_mfma_f32_16x16x32_bf16(av, *(const s8v*)&W2[32+lrow][k0], c2, 0, 0, 0);
        c3 = __builtin_amdgcn_mfma_f32_16x16x32_bf16(av, *(const s8v*)&W2[48+lrow][k0], c3, 0, 0, 0);
    }
    {
        f4v cs[4] = {c0, c1, c2, c3};
        #pragma unroll
        for (int r = 0; r < 4; ++r) {
            int n = n0 + m0 + lkg * 4 + r;
            if (n < N_NODES) {
                float* dst = io + (size_t)n * 64;
                #pragma unroll
                for (int t = 0; t < 4; ++t) dst[t * 16 + lrow] = cs[t][r] + B2[t * 16 + lrow];
            }
        }
    }
}

extern "C" void kernel_launch(void* const* d_in, const int* in_sizes, int n_in,
                              void* d_out, int out_size, void* d_ws, size_t ws_size,
                              hipStream_t stream) {
    const float* x    = (const float*)d_in[0];
    const int*   eidx = (const int*)  d_in[1];
    const float* ef   = (const float*)d_in[2];
    const float* We1  = (const float*)d_in[3];
    const float* be1  = (const float*)d_in[4];
    const float* We2  = (const float*)d_in[5];
    const float* be2  = (const float*)d_in[6];
    const float* Wn1  = (const float*)d_in[7];
    const float* bn1  = (const float*)d_in[8];
    const float* Wn2  = (const float*)d_in[9];
    const float* bn2  = (const float*)d_in[10];
    float* out = (float*)d_out;

    char* ws = (char*)d_ws;
    // ws layout (bytes)
    unsigned short* xb   = (unsigned short*)ws;                  // 12,800,000
    int*  cnt   = (int*) (ws + 12800000);                        //    400,000
    int*  basep = (int*) (ws + 13200000);                        //    400,000
    int*  cur   = (int*) (ws + 13600000);                        //    400,000
    int*  bsum  = (int*) (ws + 14000000);                        //        512
    int*  boff  = (int*) (ws + 14000512);                        //        512
    unsigned short* w1p  = (unsigned short*)(ws + 14001024);     //     20,480
    unsigned short* w2p  = (unsigned short*)(ws + 14021504);     //      8,192
    unsigned short* wn1p = (unsigned short*)(ws + 14029696);     //     16,384
    unsigned short* wn2p = (unsigned short*)(ws + 14046080);     //      8,192
    int*  elA   = (int*) (ws + 14054272);                        //  6,400,000
    us4*  efp   = (us4*) (ws + 20454272);                        // 102,400,000
    const size_t WS_NEEDED = 122854272;

    x2bf_kernel<<<1024, 256, 0, stream>>>(x, xb);

    if (ws_size >= WS_NEEDED) {
        wprep_kernel<<<64, 256, 0, stream>>>(We1, We2, Wn1, Wn2, w1p, w2p, wn1p, wn2p);
        hipMemsetAsync(cnt, 0, N_NODES * sizeof(int), stream);
        hist_kernel<<<2048, 256, 0, stream>>>(eidx, cnt);
        scanA_kernel<<<SCAN_NBLK, 1024, 0, stream>>>(cnt, basep, bsum);
        scanB_kernel<<<1, 128, 0, stream>>>(bsum, boff);
        scanC_kernel<<<(N_NODES + 255) / 256, 256, 0, stream>>>(cnt, basep, boff, cur);
        perm_kernel<<<2048, 256, 0, stream>>>(eidx, ef, cur, elA, efp);
        fused_kernel<<<(N_NODES + NPB - 1) / NPB, 512, 0, stream>>>(
            xb, basep, elA, (const unsigned short*)efp,
            w1p, w2p, wn1p, wn2p, be1, be2, bn1, bn2, out);
    } else {
        hipMemsetAsync(d_out, 0, (size_t)N_NODES * 64 * sizeof(float), stream);
        edge_kernel_fb<<<1024, 256, 0, stream>>>(xb, eidx, ef, We1, be1, We2, be2, out);
        node_kernel_fb<<<(N_NODES + 63) / 64, 256, 0, stream>>>(x, Wn1, bn1, Wn2, bn2, out);
    }
}